// Round 1
// baseline (3561.298 us; speedup 1.0000x reference)
//
#include <hip/hip_runtime.h>
#include <cstdint>
#include <cstddef>

// ---------------- problem constants ----------------
#define H_FEAT 38
#define W_FEAT 63
#define NPIX   2394        // 38*63
#define NANCH  21546       // NPIX*9
#define NSORT  32768       // next pow2 >= NANCH
#define PRE_NMS_K 6000
#define POST_NMS_K 300
#define KCONV  4608        // 512*9
#define NMS_TH 0.7f
#define MPAD   320         // fc6/fc7 padded M

typedef __bf16 bf16_t;
typedef bf16_t bf16x8 __attribute__((ext_vector_type(8)));
typedef float  f32x4  __attribute__((ext_vector_type(4)));

// canonical Faster-RCNN anchors (base 16, ratios .5/1/2, scales 8/16/32)
__device__ const float ANCHORS[9][4] = {
  { -84.f, -40.f,  99.f,  55.f}, {-176.f, -88.f, 191.f, 103.f}, {-360.f,-184.f, 375.f, 199.f},
  { -56.f, -56.f,  71.f,  71.f}, {-120.f,-120.f, 135.f, 135.f}, {-248.f,-248.f, 263.f, 263.f},
  { -36.f, -80.f,  51.f,  95.f}, { -80.f,-168.f,  95.f, 183.f}, {-168.f,-344.f, 183.f, 359.f}};

// ================= fp32 tiled NT GEMM (RPN conv only — selection path stays fp32) ==========
#define BM 64
#define BN 64
#define BK 16

template<int AMODE>
__launch_bounds__(256)
__global__ void gemm_nt(const float* __restrict__ A, const float* __restrict__ W,
                        const float* __restrict__ bias, float* __restrict__ C,
                        int M, int N, int K, int relu) {
  __shared__ float As[BK][BM];
  __shared__ float Bs[BK][BN];
  const int tid = threadIdx.x;
  const int m0 = blockIdx.y * BM;
  const int n0 = blockIdx.x * BN;
  const int lr = tid >> 2;          // 0..63 tile row
  const int lk = (tid & 3) * 4;     // k offset within BK
  const int ty = tid >> 4, tx = tid & 15;
  const int gm = m0 + lr;
  const int ph = gm / W_FEAT, pw = gm - (gm / W_FEAT) * W_FEAT;

  auto loadA = [&](int k0) -> float4 {
    if (AMODE == 0) {
      return (gm < M) ? *(const float4*)(A + (size_t)gm * K + k0 + lk)
                      : make_float4(0.f, 0.f, 0.f, 0.f);
    } else {
      float t[4];
      if (gm < M) {
#pragma unroll
        for (int q = 0; q < 4; ++q) {
          int k = k0 + lk + q;
          int ic = k / 9, tap = k - ic * 9;
          int hh = ph + tap / 3 - 1, ww = pw + (tap % 3) - 1;
          t[q] = (hh >= 0 && hh < H_FEAT && ww >= 0 && ww < W_FEAT)
                   ? A[(ic * H_FEAT + hh) * W_FEAT + ww] : 0.f;
        }
      } else { t[0] = t[1] = t[2] = t[3] = 0.f; }
      return make_float4(t[0], t[1], t[2], t[3]);
    }
  };
  auto loadB = [&](int k0) -> float4 {
    return *(const float4*)(W + (size_t)(n0 + lr) * K + k0 + lk);
  };

  float acc[4][4] = {};
  float4 av = loadA(0), bv = loadB(0);
  for (int k0 = 0; k0 < K; k0 += BK) {
    __syncthreads();
    As[lk + 0][lr] = av.x; As[lk + 1][lr] = av.y; As[lk + 2][lr] = av.z; As[lk + 3][lr] = av.w;
    Bs[lk + 0][lr] = bv.x; Bs[lk + 1][lr] = bv.y; Bs[lk + 2][lr] = bv.z; Bs[lk + 3][lr] = bv.w;
    __syncthreads();
    if (k0 + BK < K) { av = loadA(k0 + BK); bv = loadB(k0 + BK); }
#pragma unroll
    for (int kk = 0; kk < BK; ++kk) {
      float4 a = *(const float4*)&As[kk][ty * 4];
      float4 b = *(const float4*)&Bs[kk][tx * 4];
      float ar[4] = {a.x, a.y, a.z, a.w}, br[4] = {b.x, b.y, b.z, b.w};
#pragma unroll
      for (int i = 0; i < 4; ++i)
#pragma unroll
        for (int j = 0; j < 4; ++j) acc[i][j] += ar[i] * br[j];
    }
  }
  float4 bb = *(const float4*)(bias + n0 + tx * 4);
  float bb4[4] = {bb.x, bb.y, bb.z, bb.w};
#pragma unroll
  for (int i = 0; i < 4; ++i) {
    int om = m0 + ty * 4 + i;
    if (om < M) {
      float o[4];
#pragma unroll
      for (int j = 0; j < 4; ++j) {
        o[j] = acc[i][j] + bb4[j];
        if (relu) o[j] = fmaxf(o[j], 0.f);
      }
      *(float4*)(C + (size_t)om * N + n0 + tx * 4) = make_float4(o[0], o[1], o[2], o[3]);
    }
  }
}

// ================= bf16 MFMA GEMM: Cp[z] = A[Mpad,K-slice] @ W[N,K-slice]^T ================
// no LDS: A (bf16) frags direct from global (L1 serves 2x wave reuse),
// W (fp32) loaded as float4 pairs, converted to bf16 in-reg.
// block = 256 thr = 4 waves in 2x2; wave computes 32x32 (2x2 MFMA 16x16x32 tiles).
__launch_bounds__(256)
__global__ void gemm_mfma(const bf16_t* __restrict__ A, const float* __restrict__ Wt,
                          float* __restrict__ Cp, int K, int N, int kSteps,
                          size_t sliceElems) {
  const int tid = threadIdx.x;
  const int wave = tid >> 6, lane = tid & 63;
  const int l15 = lane & 15, quad = lane >> 4;
  const int wm = wave & 1, wn = wave >> 1;
  const int m0 = blockIdx.y * 64 + wm * 32;
  const int n0 = blockIdx.x * 64 + wn * 32;
  const int z = blockIdx.z;
  const int kb = z * kSteps * 32;

  const bf16_t* a0 = A + (size_t)(m0 + l15) * K + kb + quad * 8;
  const bf16_t* a1 = a0 + (size_t)16 * K;
  const float*  w0 = Wt + (size_t)(n0 + l15) * K + kb + quad * 8;
  const float*  w1 = w0 + (size_t)16 * K;

  f32x4 acc00 = {0.f, 0.f, 0.f, 0.f}, acc01 = acc00, acc10 = acc00, acc11 = acc00;

  for (int ks = 0; ks < kSteps; ++ks) {
    bf16x8 af0 = *(const bf16x8*)a0;
    bf16x8 af1 = *(const bf16x8*)a1;
    f32x4 b0a = *(const f32x4*)w0;
    f32x4 b0b = *(const f32x4*)(w0 + 4);
    f32x4 b1a = *(const f32x4*)w1;
    f32x4 b1b = *(const f32x4*)(w1 + 4);
    bf16x8 bf0, bf1;
#pragma unroll
    for (int j = 0; j < 4; ++j) {
      bf0[j] = (bf16_t)b0a[j]; bf0[j + 4] = (bf16_t)b0b[j];
      bf1[j] = (bf16_t)b1a[j]; bf1[j + 4] = (bf16_t)b1b[j];
    }
    acc00 = __builtin_amdgcn_mfma_f32_16x16x32_bf16(af0, bf0, acc00, 0, 0, 0);
    acc01 = __builtin_amdgcn_mfma_f32_16x16x32_bf16(af0, bf1, acc01, 0, 0, 0);
    acc10 = __builtin_amdgcn_mfma_f32_16x16x32_bf16(af1, bf0, acc10, 0, 0, 0);
    acc11 = __builtin_amdgcn_mfma_f32_16x16x32_bf16(af1, bf1, acc11, 0, 0, 0);
    a0 += 32; a1 += 32; w0 += 32; w1 += 32;
  }

  // C/D layout (m89-verified): col = lane&15, row = quad*4 + reg
  float* Cz = Cp + (size_t)z * sliceElems;
  const int rb = m0 + quad * 4;
#pragma unroll
  for (int i = 0; i < 4; ++i) {
    Cz[(size_t)(rb + i) * N + n0 + l15]           = acc00[i];
    Cz[(size_t)(rb + i) * N + n0 + 16 + l15]      = acc01[i];
    Cz[(size_t)(rb + 16 + i) * N + n0 + l15]      = acc10[i];
    Cz[(size_t)(rb + 16 + i) * N + n0 + 16 + l15] = acc11[i];
  }
}

// reduce split-K partials + bias + relu; optional fp32 and/or bf16 outputs.
// Safe in-place when out_f32 aliases Cp slice 0 (thread i reads idx i, writes idx i).
__global__ void epilogue_k(const float* __restrict__ Cp, size_t sliceElems, int KS,
                           const float* __restrict__ bias, int M, int N,
                           float* __restrict__ out_f32, bf16_t* __restrict__ out_bf16,
                           int relu) {
  int idx = blockIdx.x * blockDim.x + threadIdx.x;
  if (idx >= M * N) return;
  int n = idx % N;
  float s = 0.f;
  for (int z = 0; z < KS; ++z) s += Cp[(size_t)z * sliceElems + idx];
  s += bias[n];
  if (relu) s = fmaxf(s, 0.f);
  if (out_f32)  out_f32[idx]  = s;
  if (out_bf16) out_bf16[idx] = (bf16_t)s;
}

// ---------------- small-N GEMM: one thread per C element ----------------
__global__ void gemv_nt(const float* __restrict__ A, const float* __restrict__ W,
                        const float* __restrict__ bias, float* __restrict__ C,
                        int M, int N, int K, int relu) {
  int gid = blockIdx.x * blockDim.x + threadIdx.x;
  if (gid >= M * N) return;
  int m = gid / N, n = gid - m * N;
  const float* a = A + (size_t)m * K;
  const float* w = W + (size_t)n * K;
  float acc = 0.f;
  for (int k = 0; k < K; k += 4) {
    float4 x = *(const float4*)(a + k);
    float4 y = *(const float4*)(w + k);
    acc += x.x * y.x + x.y * y.y + x.z * y.z + x.w * y.w;
  }
  float o = acc + bias[n];
  if (relu) o = fmaxf(o, 0.f);
  C[gid] = o;
}

// ---------------- proposal prep: scores, boxes, sort keys ----------------
__device__ inline unsigned flip_f32(float f) {
  unsigned u = __float_as_uint(f);
  return (u & 0x80000000u) ? ~u : (u | 0x80000000u);
}

__global__ void proposal_prep(const float* __restrict__ cls,
                              const float* __restrict__ bbox,
                              const float* __restrict__ info,
                              float* __restrict__ props,
                              float* __restrict__ scores,
                              unsigned long long* __restrict__ keys) {
  int idx = blockIdx.x * blockDim.x + threadIdx.x;
  if (idx >= NSORT) return;
  unsigned long long key = 0ull;
  if (idx < NANCH) {
    int a = idx % 9, m = idx / 9;
    int h = m / W_FEAT, w = m - (m / W_FEAT) * W_FEAT;
    float s0 = cls[m * 18 + a], s1 = cls[m * 18 + 9 + a];
    float mx = fmaxf(s0, s1);
    float e0 = expf(s0 - mx), e1 = expf(s1 - mx);
    float sc = e1 / (e0 + e1);
    const float* d = bbox + m * 36 + a * 4;
    float dx = d[0], dy = d[1], dw = d[2], dh = d[3];
    float ax1 = ANCHORS[a][0] + w * 16.f, ay1 = ANCHORS[a][1] + h * 16.f;
    float ax2 = ANCHORS[a][2] + w * 16.f, ay2 = ANCHORS[a][3] + h * 16.f;
    float aw = ax2 - ax1 + 1.f, ah = ay2 - ay1 + 1.f;
    float cx = ax1 + 0.5f * aw, cy = ay1 + 0.5f * ah;
    float pcx = dx * aw + cx, pcy = dy * ah + cy;
    float pww = expf(dw) * aw, phh = expf(dh) * ah;
    float x1 = pcx - 0.5f * pww, y1 = pcy - 0.5f * phh;
    float x2 = pcx + 0.5f * pww, y2 = pcy + 0.5f * phh;
    float imh = info[0], imw = info[1], iscale = info[2];
    x1 = fminf(fmaxf(x1, 0.f), imw - 1.f);
    y1 = fminf(fmaxf(y1, 0.f), imh - 1.f);
    x2 = fminf(fmaxf(x2, 0.f), imw - 1.f);
    y2 = fminf(fmaxf(y2, 0.f), imh - 1.f);
    bool ok = (x2 - x1 + 1.f >= 16.f * iscale) && (y2 - y1 + 1.f >= 16.f * iscale);
    float s = ok ? sc : -INFINITY;
    *(float4*)(props + 4 * idx) = make_float4(x1, y1, x2, y2);
    scores[idx] = s;
    key = ((unsigned long long)flip_f32(s) << 32) |
          (unsigned long long)(0xFFFFFFFFu - (unsigned)idx);
  }
  keys[idx] = key;
}

// ---------------- bitonic sort (descending), 32768 u64 keys ----------------
__global__ void bitonic_global(unsigned long long* __restrict__ keys, int j, int k) {
  int i = blockIdx.x * blockDim.x + threadIdx.x;
  int l = i ^ j;
  if (l > i) {
    unsigned long long a = keys[i], b = keys[l];
    bool up = ((i & k) == 0);
    if (up ? (a < b) : (a > b)) { keys[i] = b; keys[l] = a; }
  }
}

__launch_bounds__(1024)
__global__ void bitonic_lds(unsigned long long* __restrict__ keys, int jstart, int k) {
  __shared__ unsigned long long s[2048];
  const int tid = threadIdx.x;
  const int base = blockIdx.x * 2048;
  s[tid] = keys[base + tid];
  s[tid + 1024] = keys[base + tid + 1024];
  __syncthreads();
  for (int j = jstart; j > 0; j >>= 1) {
    int il = ((tid & ~(j - 1)) << 1) | (tid & (j - 1));
    int ig = base + il;
    bool up = ((ig & k) == 0);
    unsigned long long a = s[il], b = s[il + j];
    if (up ? (a < b) : (a > b)) { s[il] = b; s[il + j] = a; }
    __syncthreads();
  }
  keys[base + tid] = s[tid];
  keys[base + tid + 1024] = s[tid + 1024];
}

// ---------------- NMS: single block, 6000 boxes, 300 sequential picks ----------------
__launch_bounds__(1024)
__global__ void nms_kernel(const unsigned long long* __restrict__ keys,
                           const float* __restrict__ props,
                           const float* __restrict__ scores,
                           float* __restrict__ rois_out) {
  const int tid = threadIdx.x;
  float x1[6], y1[6], x2[6], y2[6], ar[6], sc[6];
#pragma unroll
  for (int s = 0; s < 6; ++s) {
    int j = s * 1024 + tid;
    if (j < PRE_NMS_K) {
      unsigned long long k = keys[j];
      unsigned orig = 0xFFFFFFFFu - (unsigned)(k & 0xFFFFFFFFull);
      float4 b = *(const float4*)(props + 4 * (size_t)orig);
      x1[s] = b.x; y1[s] = b.y; x2[s] = b.z; y2[s] = b.w;
      ar[s] = (b.z - b.x + 1.f) * (b.w - b.y + 1.f);
      sc[s] = scores[orig];
    } else {
      x1[s] = y1[s] = x2[s] = y2[s] = 0.f; ar[s] = 0.f; sc[s] = -INFINITY;
    }
  }
  __shared__ float rs[16]; __shared__ int ri[16];
  __shared__ float rbox[5];
  const int lane = tid & 63, wid = tid >> 6;

  for (int it = 0; it < POST_NMS_K; ++it) {
    float bs = -INFINITY; int bi = 0x7FFFFFFF;
#pragma unroll
    for (int s = 0; s < 6; ++s) {
      int j = s * 1024 + tid;
      if (sc[s] > bs || (sc[s] == bs && j < bi)) { bs = sc[s]; bi = j; }
    }
#pragma unroll
    for (int off = 32; off > 0; off >>= 1) {
      float os = __shfl_down(bs, off);
      int oi = __shfl_down(bi, off);
      if (os > bs || (os == bs && oi < bi)) { bs = os; bi = oi; }
    }
    if (lane == 0) { rs[wid] = bs; ri[wid] = bi; }
    __syncthreads();
    float gs = rs[0]; int wi = ri[0];
#pragma unroll
    for (int q = 1; q < 16; ++q) {
      float qs = rs[q]; int qi = ri[q];
      if (qs > gs || (qs == gs && qi < wi)) { gs = qs; wi = qi; }
    }
    if (tid == (wi & 1023)) {
      int sl = wi >> 10;
      float vx1 = 0, vy1 = 0, vx2 = 0, vy2 = 0, va = 0;
#pragma unroll
      for (int s = 0; s < 6; ++s)
        if (s == sl) { vx1 = x1[s]; vy1 = y1[s]; vx2 = x2[s]; vy2 = y2[s]; va = ar[s]; }
      rbox[0] = vx1; rbox[1] = vy1; rbox[2] = vx2; rbox[3] = vy2; rbox[4] = va;
      *(float4*)(rois_out + it * 4) = make_float4(vx1, vy1, vx2, vy2);
    }
    __syncthreads();
    float bx1 = rbox[0], by1 = rbox[1], bx2 = rbox[2], by2 = rbox[3], ba = rbox[4];
#pragma unroll
    for (int s = 0; s < 6; ++s) {
      float xx1 = fmaxf(bx1, x1[s]), yy1 = fmaxf(by1, y1[s]);
      float xx2 = fminf(bx2, x2[s]), yy2 = fminf(by2, y2[s]);
      float iw = fmaxf(xx2 - xx1 + 1.f, 0.f), ih = fmaxf(yy2 - yy1 + 1.f, 0.f);
      float inter = iw * ih;
      float iou = inter / (ba + ar[s] - inter);
      if (iou > NMS_TH) sc[s] = -INFINITY;
    }
  }
}

// ---------------- ROI max pooling -> bf16 ----------------
__global__ void roi_pool(const float* __restrict__ feat,
                         const float* __restrict__ rois,
                         bf16_t* __restrict__ out) {   // (MPAD rows x 25088), rows 0..299 written
  const int r = blockIdx.x;
  const float4 roi = *(const float4*)(rois + 4 * r);
  float rsw = rintf(roi.x * 0.0625f);
  float rsh = rintf(roi.y * 0.0625f);
  float rew = rintf(roi.z * 0.0625f);
  float reh = rintf(roi.w * 0.0625f);
  float bw = fmaxf(rew - rsw + 1.f, 1.f) / 7.f;
  float bh = fmaxf(reh - rsh + 1.f, 1.f) / 7.f;
  for (int idx = threadIdx.x; idx < 512 * 49; idx += blockDim.x) {
    int c = idx / 49, b = idx - c * 49;
    int ph = b / 7, pw = b - ph * 7;
    float hs = fminf(fmaxf(floorf(ph * bh) + rsh, 0.f), (float)H_FEAT);
    float he = fminf(fmaxf(ceilf((ph + 1) * bh) + rsh, 0.f), (float)H_FEAT);
    float wS = fminf(fmaxf(floorf(pw * bw) + rsw, 0.f), (float)W_FEAT);
    float wE = fminf(fmaxf(ceilf((pw + 1) * bw) + rsw, 0.f), (float)W_FEAT);
    int h0 = (int)hs, h1 = (int)he, w0 = (int)wS, w1 = (int)wE;
    float m = -1e30f;
    const float* fc = feat + (size_t)c * (H_FEAT * W_FEAT);
    for (int h = h0; h < h1; ++h)
      for (int w = w0; w < w1; ++w)
        m = fmaxf(m, fc[h * W_FEAT + w]);
    out[(size_t)r * 25088 + idx] = (bf16_t)((m < -1e29f) ? 0.f : m);
  }
}

// ---------------- row softmax (300 x 32) ----------------
__global__ void softmax32(const float* __restrict__ in, float* __restrict__ out) {
  int r = blockIdx.x * blockDim.x + threadIdx.x;
  if (r >= POST_NMS_K) return;
  const float* x = in + r * 32;
  float m = x[0];
#pragma unroll
  for (int k = 1; k < 32; ++k) m = fmaxf(m, x[k]);
  float e[32]; float s = 0.f;
#pragma unroll
  for (int k = 0; k < 32; ++k) { e[k] = expf(x[k] - m); s += e[k]; }
  float inv = 1.f / s;
#pragma unroll
  for (int k = 0; k < 32; ++k) out[r * 32 + k] = e[k] * inv;
}

// ---------------- launch ----------------
extern "C" void kernel_launch(void* const* d_in, const int* in_sizes, int n_in,
                              void* d_out, int out_size, void* d_ws, size_t ws_size,
                              hipStream_t stream) {
  const float* feat    = (const float*)d_in[0];
  const float* info    = (const float*)d_in[1];
  const float* conv1_w = (const float*)d_in[2];
  const float* conv1_b = (const float*)d_in[3];
  const float* score_w = (const float*)d_in[4];
  const float* score_b = (const float*)d_in[5];
  const float* bbox_w  = (const float*)d_in[6];
  const float* bbox_b  = (const float*)d_in[7];
  const float* fc6_w   = (const float*)d_in[8];
  const float* fc6_b   = (const float*)d_in[9];
  const float* fc7_w   = (const float*)d_in[10];
  const float* fc7_b   = (const float*)d_in[11];
  const float* sfc_w   = (const float*)d_in[12];
  const float* sfc_b   = (const float*)d_in[13];
  const float* bfc_w   = (const float*)d_in[14];
  const float* bfc_b   = (const float*)d_in[15];
  float* out = (float*)d_out;
  char*  ws  = (char*)d_ws;

  size_t off = 0;
  auto alloc = [&](size_t bytes) { size_t o = off; off += (bytes + 255) & ~(size_t)255; return o; };
  float* cls    = (float*)(ws + alloc((size_t)NPIX * 18 * 4));
  float* bbx    = (float*)(ws + alloc((size_t)NPIX * 36 * 4));
  float* props  = (float*)(ws + alloc((size_t)NANCH * 4 * 4));
  float* scores = (float*)(ws + alloc((size_t)NANCH * 4));
  unsigned long long* keys = (unsigned long long*)(ws + alloc((size_t)NSORT * 8));
  float* rpn    = (float*)(ws + alloc((size_t)NPIX * 512 * 4));
  // pooled region (bf16, 320x25088 = 16.06MB) is dead after fc6 GEMM; fc7 partials overlay it.
  char*  pooled_raw = ws + alloc((size_t)MPAD * 25088 * 2);
  bf16_t* pooled = (bf16_t*)pooled_raw;
  float*  fc7P   = (float*)pooled_raw;                 // 2 x 320*4096*4 = 10.49MB  (overlay)
  float*  fc7o   = fc7P;                               // epilogue in-place on slice 0
  float* fc6P    = (float*)(ws + alloc((size_t)4 * MPAD * 4096 * 4));
  bf16_t* fc6bf  = (bf16_t*)(ws + alloc((size_t)MPAD * 4096 * 2));
  float* clsfc   = (float*)(ws + alloc((size_t)POST_NMS_K * 32 * 4));

  float* rois_out = out + 9600 + 38400;   // cls_prob(300x32) | box(300x128) | rois(300x4)

  // 1. RPN conv 3x3 + relu (fp32 — selection path must stay bit-stable)
  gemm_nt<1><<<dim3(512 / BN, (NPIX + BM - 1) / BM), 256, 0, stream>>>(
      feat, conv1_w, conv1_b, rpn, NPIX, 512, KCONV, 1);
  // 2. 1x1 convs (fp32)
  gemv_nt<<<(NPIX * 18 + 255) / 256, 256, 0, stream>>>(rpn, score_w, score_b, cls, NPIX, 18, 512, 0);
  gemv_nt<<<(NPIX * 36 + 255) / 256, 256, 0, stream>>>(rpn, bbox_w, bbox_b, bbx, NPIX, 36, 512, 0);
  // 3. proposals + sort keys
  proposal_prep<<<NSORT / 256, 256, 0, stream>>>(cls, bbx, info, props, scores, keys);
  // 4. bitonic sort, descending
  for (int k = 2; k <= 2048; k <<= 1)
    bitonic_lds<<<NSORT / 2048, 1024, 0, stream>>>(keys, k >> 1, k);
  for (int k = 4096; k <= NSORT; k <<= 1) {
    for (int j = k >> 1; j >= 2048; j >>= 1)
      bitonic_global<<<NSORT / 256, 256, 0, stream>>>(keys, j, k);
    bitonic_lds<<<NSORT / 2048, 1024, 0, stream>>>(keys, 1024, k);
  }
  // 5. NMS -> rois (to d_out)
  nms_kernel<<<1, 1024, 0, stream>>>(keys, props, scores, rois_out);
  // 6. ROI max-pool -> bf16
  roi_pool<<<POST_NMS_K, 256, 0, stream>>>(feat, rois_out, pooled);
  // 7. fc6: bf16 MFMA, split-K=4 (64x5x4 = 1280 blocks), then reduce+bias+relu -> bf16
  gemm_mfma<<<dim3(64, MPAD / 64, 4), 256, 0, stream>>>(
      pooled, fc6_w, fc6P, 25088, 4096, 25088 / 32 / 4, (size_t)MPAD * 4096);
  epilogue_k<<<(POST_NMS_K * 4096 + 255) / 256, 256, 0, stream>>>(
      fc6P, (size_t)MPAD * 4096, 4, fc6_b, POST_NMS_K, 4096, nullptr, fc6bf, 1);
  // 8. fc7: bf16 MFMA, split-K=2, epilogue in-place -> fp32
  gemm_mfma<<<dim3(64, MPAD / 64, 2), 256, 0, stream>>>(
      fc6bf, fc7_w, fc7P, 4096, 4096, 4096 / 32 / 2, (size_t)MPAD * 4096);
  epilogue_k<<<(POST_NMS_K * 4096 + 255) / 256, 256, 0, stream>>>(
      fc7P, (size_t)MPAD * 4096, 2, fc7_b, POST_NMS_K, 4096, fc7o, nullptr, 1);
  // 9. heads (fp32)
  gemv_nt<<<(POST_NMS_K * 32 + 255) / 256, 256, 0, stream>>>(fc7o, sfc_w, sfc_b, clsfc, POST_NMS_K, 32, 4096, 0);
  softmax32<<<(POST_NMS_K + 63) / 64, 64, 0, stream>>>(clsfc, out);
  gemv_nt<<<(POST_NMS_K * 128 + 255) / 256, 256, 0, stream>>>(fc7o, bfc_w, bfc_b, out + 9600, POST_NMS_K, 128, 4096, 0);
}

// Round 2
// 2795.266 us; speedup vs baseline: 1.2740x; 1.2740x over previous
//
#include <hip/hip_runtime.h>
#include <cstdint>
#include <cstddef>

// ---------------- problem constants ----------------
#define H_FEAT 38
#define W_FEAT 63
#define NPIX   2394        // 38*63
#define NANCH  21546       // NPIX*9
#define NSORT  32768       // next pow2 >= NANCH
#define PRE_NMS_K 6000
#define POST_NMS_K 300
#define KCONV  4608        // 512*9
#define NMS_TH 0.7f
#define MPAD   320         // fc6/fc7 padded M
#define NW64   94          // ceil(6000/64) words of suppression bitmask
#define NPAD   6016        // NW64*64

typedef __bf16 bf16_t;
typedef bf16_t bf16x8 __attribute__((ext_vector_type(8)));
typedef float  f32x4  __attribute__((ext_vector_type(4)));

// canonical Faster-RCNN anchors (base 16, ratios .5/1/2, scales 8/16/32)
__device__ const float ANCHORS[9][4] = {
  { -84.f, -40.f,  99.f,  55.f}, {-176.f, -88.f, 191.f, 103.f}, {-360.f,-184.f, 375.f, 199.f},
  { -56.f, -56.f,  71.f,  71.f}, {-120.f,-120.f, 135.f, 135.f}, {-248.f,-248.f, 263.f, 263.f},
  { -36.f, -80.f,  51.f,  95.f}, { -80.f,-168.f,  95.f, 183.f}, {-168.f,-344.f, 183.f, 359.f}};

// ================= fp32 tiled NT GEMM (RPN conv only — selection path stays fp32) ==========
#define BM 64
#define BN 64
#define BK 16

template<int AMODE>
__launch_bounds__(256)
__global__ void gemm_nt(const float* __restrict__ A, const float* __restrict__ W,
                        const float* __restrict__ bias, float* __restrict__ C,
                        int M, int N, int K, int relu) {
  __shared__ float As[BK][BM];
  __shared__ float Bs[BK][BN];
  const int tid = threadIdx.x;
  const int m0 = blockIdx.y * BM;
  const int n0 = blockIdx.x * BN;
  const int lr = tid >> 2;          // 0..63 tile row
  const int lk = (tid & 3) * 4;     // k offset within BK
  const int ty = tid >> 4, tx = tid & 15;
  const int gm = m0 + lr;
  const int ph = gm / W_FEAT, pw = gm - (gm / W_FEAT) * W_FEAT;

  auto loadA = [&](int k0) -> float4 {
    if (AMODE == 0) {
      return (gm < M) ? *(const float4*)(A + (size_t)gm * K + k0 + lk)
                      : make_float4(0.f, 0.f, 0.f, 0.f);
    } else {
      float t[4];
      if (gm < M) {
#pragma unroll
        for (int q = 0; q < 4; ++q) {
          int k = k0 + lk + q;
          int ic = k / 9, tap = k - ic * 9;
          int hh = ph + tap / 3 - 1, ww = pw + (tap % 3) - 1;
          t[q] = (hh >= 0 && hh < H_FEAT && ww >= 0 && ww < W_FEAT)
                   ? A[(ic * H_FEAT + hh) * W_FEAT + ww] : 0.f;
        }
      } else { t[0] = t[1] = t[2] = t[3] = 0.f; }
      return make_float4(t[0], t[1], t[2], t[3]);
    }
  };
  auto loadB = [&](int k0) -> float4 {
    return *(const float4*)(W + (size_t)(n0 + lr) * K + k0 + lk);
  };

  float acc[4][4] = {};
  float4 av = loadA(0), bv = loadB(0);
  for (int k0 = 0; k0 < K; k0 += BK) {
    __syncthreads();
    As[lk + 0][lr] = av.x; As[lk + 1][lr] = av.y; As[lk + 2][lr] = av.z; As[lk + 3][lr] = av.w;
    Bs[lk + 0][lr] = bv.x; Bs[lk + 1][lr] = bv.y; Bs[lk + 2][lr] = bv.z; Bs[lk + 3][lr] = bv.w;
    __syncthreads();
    if (k0 + BK < K) { av = loadA(k0 + BK); bv = loadB(k0 + BK); }
#pragma unroll
    for (int kk = 0; kk < BK; ++kk) {
      float4 a = *(const float4*)&As[kk][ty * 4];
      float4 b = *(const float4*)&Bs[kk][tx * 4];
      float ar[4] = {a.x, a.y, a.z, a.w}, br[4] = {b.x, b.y, b.z, b.w};
#pragma unroll
      for (int i = 0; i < 4; ++i)
#pragma unroll
        for (int j = 0; j < 4; ++j) acc[i][j] += ar[i] * br[j];
    }
  }
  float4 bb = *(const float4*)(bias + n0 + tx * 4);
  float bb4[4] = {bb.x, bb.y, bb.z, bb.w};
#pragma unroll
  for (int i = 0; i < 4; ++i) {
    int om = m0 + ty * 4 + i;
    if (om < M) {
      float o[4];
#pragma unroll
      for (int j = 0; j < 4; ++j) {
        o[j] = acc[i][j] + bb4[j];
        if (relu) o[j] = fmaxf(o[j], 0.f);
      }
      *(float4*)(C + (size_t)om * N + n0 + tx * 4) = make_float4(o[0], o[1], o[2], o[3]);
    }
  }
}

// ================= bf16 MFMA GEMM: Cp[z] = A[Mpad,K-slice] @ W[N,K-slice]^T ================
__launch_bounds__(256)
__global__ void gemm_mfma(const bf16_t* __restrict__ A, const float* __restrict__ Wt,
                          float* __restrict__ Cp, int K, int N, int kSteps,
                          size_t sliceElems) {
  const int tid = threadIdx.x;
  const int wave = tid >> 6, lane = tid & 63;
  const int l15 = lane & 15, quad = lane >> 4;
  const int wm = wave & 1, wn = wave >> 1;
  const int m0 = blockIdx.y * 64 + wm * 32;
  const int n0 = blockIdx.x * 64 + wn * 32;
  const int z = blockIdx.z;
  const int kb = z * kSteps * 32;

  const bf16_t* a0 = A + (size_t)(m0 + l15) * K + kb + quad * 8;
  const bf16_t* a1 = a0 + (size_t)16 * K;
  const float*  w0 = Wt + (size_t)(n0 + l15) * K + kb + quad * 8;
  const float*  w1 = w0 + (size_t)16 * K;

  f32x4 acc00 = {0.f, 0.f, 0.f, 0.f}, acc01 = acc00, acc10 = acc00, acc11 = acc00;

  for (int ks = 0; ks < kSteps; ++ks) {
    bf16x8 af0 = *(const bf16x8*)a0;
    bf16x8 af1 = *(const bf16x8*)a1;
    f32x4 b0a = *(const f32x4*)w0;
    f32x4 b0b = *(const f32x4*)(w0 + 4);
    f32x4 b1a = *(const f32x4*)w1;
    f32x4 b1b = *(const f32x4*)(w1 + 4);
    bf16x8 bf0, bf1;
#pragma unroll
    for (int j = 0; j < 4; ++j) {
      bf0[j] = (bf16_t)b0a[j]; bf0[j + 4] = (bf16_t)b0b[j];
      bf1[j] = (bf16_t)b1a[j]; bf1[j + 4] = (bf16_t)b1b[j];
    }
    acc00 = __builtin_amdgcn_mfma_f32_16x16x32_bf16(af0, bf0, acc00, 0, 0, 0);
    acc01 = __builtin_amdgcn_mfma_f32_16x16x32_bf16(af0, bf1, acc01, 0, 0, 0);
    acc10 = __builtin_amdgcn_mfma_f32_16x16x32_bf16(af1, bf0, acc10, 0, 0, 0);
    acc11 = __builtin_amdgcn_mfma_f32_16x16x32_bf16(af1, bf1, acc11, 0, 0, 0);
    a0 += 32; a1 += 32; w0 += 32; w1 += 32;
  }

  // C/D layout (m89-verified): col = lane&15, row = quad*4 + reg
  float* Cz = Cp + (size_t)z * sliceElems;
  const int rb = m0 + quad * 4;
#pragma unroll
  for (int i = 0; i < 4; ++i) {
    Cz[(size_t)(rb + i) * N + n0 + l15]           = acc00[i];
    Cz[(size_t)(rb + i) * N + n0 + 16 + l15]      = acc01[i];
    Cz[(size_t)(rb + 16 + i) * N + n0 + l15]      = acc10[i];
    Cz[(size_t)(rb + 16 + i) * N + n0 + 16 + l15] = acc11[i];
  }
}

// reduce split-K partials + bias + relu; optional fp32 and/or bf16 outputs.
__global__ void epilogue_k(const float* __restrict__ Cp, size_t sliceElems, int KS,
                           const float* __restrict__ bias, int M, int N,
                           float* __restrict__ out_f32, bf16_t* __restrict__ out_bf16,
                           int relu) {
  int idx = blockIdx.x * blockDim.x + threadIdx.x;
  if (idx >= M * N) return;
  int n = idx % N;
  float s = 0.f;
  for (int z = 0; z < KS; ++z) s += Cp[(size_t)z * sliceElems + idx];
  s += bias[n];
  if (relu) s = fmaxf(s, 0.f);
  if (out_f32)  out_f32[idx]  = s;
  if (out_bf16) out_bf16[idx] = (bf16_t)s;
}

// ---------------- small-N GEMM: one thread per C element ----------------
__global__ void gemv_nt(const float* __restrict__ A, const float* __restrict__ W,
                        const float* __restrict__ bias, float* __restrict__ C,
                        int M, int N, int K, int relu) {
  int gid = blockIdx.x * blockDim.x + threadIdx.x;
  if (gid >= M * N) return;
  int m = gid / N, n = gid - m * N;
  const float* a = A + (size_t)m * K;
  const float* w = W + (size_t)n * K;
  float acc = 0.f;
  for (int k = 0; k < K; k += 4) {
    float4 x = *(const float4*)(a + k);
    float4 y = *(const float4*)(w + k);
    acc += x.x * y.x + x.y * y.y + x.z * y.z + x.w * y.w;
  }
  float o = acc + bias[n];
  if (relu) o = fmaxf(o, 0.f);
  C[gid] = o;
}

// ---------------- proposal prep: scores, boxes, sort keys ----------------
__device__ inline unsigned flip_f32(float f) {
  unsigned u = __float_as_uint(f);
  return (u & 0x80000000u) ? ~u : (u | 0x80000000u);
}

__global__ void proposal_prep(const float* __restrict__ cls,
                              const float* __restrict__ bbox,
                              const float* __restrict__ info,
                              float* __restrict__ props,
                              float* __restrict__ scores,
                              unsigned long long* __restrict__ keys) {
  int idx = blockIdx.x * blockDim.x + threadIdx.x;
  if (idx >= NSORT) return;
  unsigned long long key = 0ull;
  if (idx < NANCH) {
    int a = idx % 9, m = idx / 9;
    int h = m / W_FEAT, w = m - (m / W_FEAT) * W_FEAT;
    float s0 = cls[m * 18 + a], s1 = cls[m * 18 + 9 + a];
    float mx = fmaxf(s0, s1);
    float e0 = expf(s0 - mx), e1 = expf(s1 - mx);
    float sc = e1 / (e0 + e1);
    const float* d = bbox + m * 36 + a * 4;
    float dx = d[0], dy = d[1], dw = d[2], dh = d[3];
    float ax1 = ANCHORS[a][0] + w * 16.f, ay1 = ANCHORS[a][1] + h * 16.f;
    float ax2 = ANCHORS[a][2] + w * 16.f, ay2 = ANCHORS[a][3] + h * 16.f;
    float aw = ax2 - ax1 + 1.f, ah = ay2 - ay1 + 1.f;
    float cx = ax1 + 0.5f * aw, cy = ay1 + 0.5f * ah;
    float pcx = dx * aw + cx, pcy = dy * ah + cy;
    float pww = expf(dw) * aw, phh = expf(dh) * ah;
    float x1 = pcx - 0.5f * pww, y1 = pcy - 0.5f * phh;
    float x2 = pcx + 0.5f * pww, y2 = pcy + 0.5f * phh;
    float imh = info[0], imw = info[1], iscale = info[2];
    x1 = fminf(fmaxf(x1, 0.f), imw - 1.f);
    y1 = fminf(fmaxf(y1, 0.f), imh - 1.f);
    x2 = fminf(fmaxf(x2, 0.f), imw - 1.f);
    y2 = fminf(fmaxf(y2, 0.f), imh - 1.f);
    bool ok = (x2 - x1 + 1.f >= 16.f * iscale) && (y2 - y1 + 1.f >= 16.f * iscale);
    float s = ok ? sc : -INFINITY;
    *(float4*)(props + 4 * idx) = make_float4(x1, y1, x2, y2);
    scores[idx] = s;
    key = ((unsigned long long)flip_f32(s) << 32) |
          (unsigned long long)(0xFFFFFFFFu - (unsigned)idx);
  }
  keys[idx] = key;
}

// ---------------- bitonic sort (descending), 32768 u64 keys ----------------
__global__ void bitonic_global(unsigned long long* __restrict__ keys, int j, int k) {
  int i = blockIdx.x * blockDim.x + threadIdx.x;
  int l = i ^ j;
  if (l > i) {
    unsigned long long a = keys[i], b = keys[l];
    bool up = ((i & k) == 0);
    if (up ? (a < b) : (a > b)) { keys[i] = b; keys[l] = a; }
  }
}

__launch_bounds__(1024)
__global__ void bitonic_lds(unsigned long long* __restrict__ keys, int jstart, int k) {
  __shared__ unsigned long long s[2048];
  const int tid = threadIdx.x;
  const int base = blockIdx.x * 2048;
  s[tid] = keys[base + tid];
  s[tid + 1024] = keys[base + tid + 1024];
  __syncthreads();
  for (int j = jstart; j > 0; j >>= 1) {
    int il = ((tid & ~(j - 1)) << 1) | (tid & (j - 1));
    int ig = base + il;
    bool up = ((ig & k) == 0);
    unsigned long long a = s[il], b = s[il + j];
    if (up ? (a < b) : (a > b)) { s[il] = b; s[il + j] = a; }
    __syncthreads();
  }
  keys[base + tid] = s[tid];
  keys[base + tid + 1024] = s[tid + 1024];
}

// ================= NMS v2: parallel IoU bitmask + single-wave greedy scan ==========
// gather sorted top-6000 boxes into contiguous arrays + validity ballot
__global__ void nms_gather(const unsigned long long* __restrict__ keys,
                           const float* __restrict__ props,
                           const float* __restrict__ scores,
                           float4* __restrict__ sbox, float* __restrict__ sarea,
                           float* __restrict__ sscore,
                           unsigned long long* __restrict__ vmask) {
  int j = blockIdx.x * blockDim.x + threadIdx.x;
  bool valid = false;
  float4 b = make_float4(0.f, 0.f, 0.f, 0.f);
  float s = -INFINITY, area = 0.f;
  if (j < PRE_NMS_K) {
    unsigned long long k = keys[j];
    unsigned orig = 0xFFFFFFFFu - (unsigned)(k & 0xFFFFFFFFull);
    b = *(const float4*)(props + 4 * (size_t)orig);
    s = scores[orig];
    area = (b.z - b.x + 1.f) * (b.w - b.y + 1.f);
    valid = (s != -INFINITY);
  }
  if (j < NPAD) { sbox[j] = b; sarea[j] = area; sscore[j] = s; }
  unsigned long long ball = __ballot(valid);
  if ((threadIdx.x & 63) == 0 && j < NPAD) vmask[j >> 6] = ball;
}

// mask[j][w] bit b = (iou(box j, box w*64+b) > NMS_TH)
// IoU operand order identical to reference: inter / (area_picked + area_other - inter)
__global__ void nms_mask(const float4* __restrict__ sbox, const float* __restrict__ sarea,
                         unsigned long long* __restrict__ mask) {
  int idx = blockIdx.x * blockDim.x + threadIdx.x;
  if (idx >= NPAD * NW64) return;
  int j = idx / NW64, w = idx - j * NW64;
  float4 bj = sbox[j];
  float aj = sarea[j];
  unsigned long long m = 0ull;
  int kbase = w * 64;
#pragma unroll 8
  for (int b = 0; b < 64; ++b) {
    int k = kbase + b;
    float4 bk = sbox[k];
    float xx1 = fmaxf(bj.x, bk.x), yy1 = fmaxf(bj.y, bk.y);
    float xx2 = fminf(bj.z, bk.z), yy2 = fminf(bj.w, bk.w);
    float iw = fmaxf(xx2 - xx1 + 1.f, 0.f), ih = fmaxf(yy2 - yy1 + 1.f, 0.f);
    float inter = iw * ih;
    float iou = inter / (aj + sarea[k] - inter);
    if (iou > NMS_TH) m |= (1ull << b);
  }
  mask[(size_t)j * NW64 + w] = m;
}

// single-wave greedy scan. Suppressed mask distributed: lane l owns words 2l, 2l+1.
// Greedy over sorted order == reference's iterative argmax+suppress (ties already
// resolved by sort keys; suppressed boxes never suppress; -inf boxes skipped via vmask;
// if <300 keeps, remaining picks replicate sorted position 0 (argmax of all -inf)).
__launch_bounds__(64)
__global__ void nms_scan(const float4* __restrict__ sbox,
                         const unsigned long long* __restrict__ vmask,
                         const unsigned long long* __restrict__ mask,
                         float* __restrict__ rois_out) {
  const int lane = threadIdx.x;
  const int w0 = 2 * lane, w1 = 2 * lane + 1;
  unsigned long long S0 = 0ull, S1 = 0ull;
  const unsigned long long V0 = (w0 < NW64) ? vmask[w0] : 0ull;
  const unsigned long long V1 = (w1 < NW64) ? vmask[w1] : 0ull;
  __shared__ int keepIdx[POST_NMS_K];
  int keeps = 0;
  for (int w = 0; w < NW64 && keeps < POST_NMS_K; ++w) {
    const int owner = w >> 1;
    unsigned long long candsrc = (w & 1) ? ((~S1) & V1) : ((~S0) & V0);
    unsigned long long cw = __shfl(candsrc, owner);
    while (cw) {
      int b = __builtin_ctzll(cw);
      int j = w * 64 + b;
      if (lane == 0) keepIdx[keeps] = j;
      keeps++;
      if (keeps == POST_NMS_K) break;
      const unsigned long long* row = mask + (size_t)j * NW64;
      if (w0 < NW64) S0 |= row[w0];
      if (w1 < NW64) S1 |= row[w1];
      candsrc = (w & 1) ? ((~S1) & V1) : ((~S0) & V0);
      unsigned long long hi = (b == 63) ? 0ull : (~0ull << (b + 1));
      cw = __shfl(candsrc, owner) & hi;
    }
  }
  __syncthreads();
  for (int t = lane; t < POST_NMS_K; t += 64) {
    int j = (t < keeps) ? keepIdx[t] : 0;   // degenerate fill = sorted position 0
    float4 bx = sbox[j];
    *(float4*)(rois_out + 4 * t) = bx;
  }
}

// ---------------- ROI max pooling -> bf16 ----------------
__global__ void roi_pool(const float* __restrict__ feat,
                         const float* __restrict__ rois,
                         bf16_t* __restrict__ out) {   // (MPAD rows x 25088), rows 0..299 written
  const int r = blockIdx.x;
  const float4 roi = *(const float4*)(rois + 4 * r);
  float rsw = rintf(roi.x * 0.0625f);
  float rsh = rintf(roi.y * 0.0625f);
  float rew = rintf(roi.z * 0.0625f);
  float reh = rintf(roi.w * 0.0625f);
  float bw = fmaxf(rew - rsw + 1.f, 1.f) / 7.f;
  float bh = fmaxf(reh - rsh + 1.f, 1.f) / 7.f;
  for (int idx = threadIdx.x; idx < 512 * 49; idx += blockDim.x) {
    int c = idx / 49, b = idx - c * 49;
    int ph = b / 7, pw = b - ph * 7;
    float hs = fminf(fmaxf(floorf(ph * bh) + rsh, 0.f), (float)H_FEAT);
    float he = fminf(fmaxf(ceilf((ph + 1) * bh) + rsh, 0.f), (float)H_FEAT);
    float wS = fminf(fmaxf(floorf(pw * bw) + rsw, 0.f), (float)W_FEAT);
    float wE = fminf(fmaxf(ceilf((pw + 1) * bw) + rsw, 0.f), (float)W_FEAT);
    int h0 = (int)hs, h1 = (int)he, w0 = (int)wS, w1 = (int)wE;
    float m = -1e30f;
    const float* fc = feat + (size_t)c * (H_FEAT * W_FEAT);
    for (int h = h0; h < h1; ++h)
      for (int w = w0; w < w1; ++w)
        m = fmaxf(m, fc[h * W_FEAT + w]);
    out[(size_t)r * 25088 + idx] = (bf16_t)((m < -1e29f) ? 0.f : m);
  }
}

// ---------------- row softmax (300 x 32) ----------------
__global__ void softmax32(const float* __restrict__ in, float* __restrict__ out) {
  int r = blockIdx.x * blockDim.x + threadIdx.x;
  if (r >= POST_NMS_K) return;
  const float* x = in + r * 32;
  float m = x[0];
#pragma unroll
  for (int k = 1; k < 32; ++k) m = fmaxf(m, x[k]);
  float e[32]; float s = 0.f;
#pragma unroll
  for (int k = 0; k < 32; ++k) { e[k] = expf(x[k] - m); s += e[k]; }
  float inv = 1.f / s;
#pragma unroll
  for (int k = 0; k < 32; ++k) out[r * 32 + k] = e[k] * inv;
}

// ---------------- launch ----------------
extern "C" void kernel_launch(void* const* d_in, const int* in_sizes, int n_in,
                              void* d_out, int out_size, void* d_ws, size_t ws_size,
                              hipStream_t stream) {
  const float* feat    = (const float*)d_in[0];
  const float* info    = (const float*)d_in[1];
  const float* conv1_w = (const float*)d_in[2];
  const float* conv1_b = (const float*)d_in[3];
  const float* score_w = (const float*)d_in[4];
  const float* score_b = (const float*)d_in[5];
  const float* bbox_w  = (const float*)d_in[6];
  const float* bbox_b  = (const float*)d_in[7];
  const float* fc6_w   = (const float*)d_in[8];
  const float* fc6_b   = (const float*)d_in[9];
  const float* fc7_w   = (const float*)d_in[10];
  const float* fc7_b   = (const float*)d_in[11];
  const float* sfc_w   = (const float*)d_in[12];
  const float* sfc_b   = (const float*)d_in[13];
  const float* bfc_w   = (const float*)d_in[14];
  const float* bfc_b   = (const float*)d_in[15];
  float* out = (float*)d_out;
  char*  ws  = (char*)d_ws;

  size_t off = 0;
  auto alloc = [&](size_t bytes) { size_t o = off; off += (bytes + 255) & ~(size_t)255; return o; };
  float* cls    = (float*)(ws + alloc((size_t)NPIX * 18 * 4));
  float* bbx    = (float*)(ws + alloc((size_t)NPIX * 36 * 4));
  float* props  = (float*)(ws + alloc((size_t)NANCH * 4 * 4));
  float* scores = (float*)(ws + alloc((size_t)NANCH * 4));
  unsigned long long* keys = (unsigned long long*)(ws + alloc((size_t)NSORT * 8));
  float* rpn    = (float*)(ws + alloc((size_t)NPIX * 512 * 4));
  // pooled region (bf16, 320x25088 = 16.06MB) is dead after fc6 GEMM; fc7 partials overlay it.
  char*  pooled_raw = ws + alloc((size_t)MPAD * 25088 * 2);
  bf16_t* pooled = (bf16_t*)pooled_raw;
  float*  fc7P   = (float*)pooled_raw;                 // 2 x 320*4096*4 = 10.49MB  (overlay)
  float*  fc7o   = fc7P;                               // epilogue in-place on slice 0
  float* fc6P    = (float*)(ws + alloc((size_t)4 * MPAD * 4096 * 4));
  bf16_t* fc6bf  = (bf16_t*)(ws + alloc((size_t)MPAD * 4096 * 2));
  float* clsfc   = (float*)(ws + alloc((size_t)POST_NMS_K * 32 * 4));

  // NMS scratch overlays fc6P (21.5MB; dead until fc6 GEMM which launches after nms_scan)
  char* nmsbase = (char*)fc6P;
  float4* sbox  = (float4*)nmsbase;                            // 6016*16  = 96256
  float*  sarea = (float*)(nmsbase + 96256);                   // 6016*4   = 24064
  float*  sscore= (float*)(nmsbase + 120320);                  // 6016*4   = 24064
  unsigned long long* vmask = (unsigned long long*)(nmsbase + 144384);  // 94*8
  unsigned long long* maskb = (unsigned long long*)(nmsbase + 145408);  // 6016*94*8 = 4.52MB

  float* rois_out = out + 9600 + 38400;   // cls_prob(300x32) | box(300x128) | rois(300x4)

  // 1. RPN conv 3x3 + relu (fp32 — selection path must stay bit-stable)
  gemm_nt<1><<<dim3(512 / BN, (NPIX + BM - 1) / BM), 256, 0, stream>>>(
      feat, conv1_w, conv1_b, rpn, NPIX, 512, KCONV, 1);
  // 2. 1x1 convs (fp32)
  gemv_nt<<<(NPIX * 18 + 255) / 256, 256, 0, stream>>>(rpn, score_w, score_b, cls, NPIX, 18, 512, 0);
  gemv_nt<<<(NPIX * 36 + 255) / 256, 256, 0, stream>>>(rpn, bbox_w, bbox_b, bbx, NPIX, 36, 512, 0);
  // 3. proposals + sort keys
  proposal_prep<<<NSORT / 256, 256, 0, stream>>>(cls, bbx, info, props, scores, keys);
  // 4. bitonic sort, descending
  for (int k = 2; k <= 2048; k <<= 1)
    bitonic_lds<<<NSORT / 2048, 1024, 0, stream>>>(keys, k >> 1, k);
  for (int k = 4096; k <= NSORT; k <<= 1) {
    for (int j = k >> 1; j >= 2048; j >>= 1)
      bitonic_global<<<NSORT / 256, 256, 0, stream>>>(keys, j, k);
    bitonic_lds<<<NSORT / 2048, 1024, 0, stream>>>(keys, 1024, k);
  }
  // 5. NMS v2: gather -> parallel IoU bitmask -> single-wave greedy scan
  nms_gather<<<(NPAD + 255) / 256, 256, 0, stream>>>(keys, props, scores, sbox, sarea, sscore, vmask);
  nms_mask<<<(NPAD * NW64 + 255) / 256, 256, 0, stream>>>(sbox, sarea, maskb);
  nms_scan<<<1, 64, 0, stream>>>(sbox, vmask, maskb, rois_out);
  // 6. ROI max-pool -> bf16
  roi_pool<<<POST_NMS_K, 256, 0, stream>>>(feat, rois_out, pooled);
  // 7. fc6: bf16 MFMA, split-K=4 (64x5x4 = 1280 blocks), then reduce+bias+relu -> bf16
  gemm_mfma<<<dim3(64, MPAD / 64, 4), 256, 0, stream>>>(
      pooled, fc6_w, fc6P, 25088, 4096, 25088 / 32 / 4, (size_t)MPAD * 4096);
  epilogue_k<<<(POST_NMS_K * 4096 + 255) / 256, 256, 0, stream>>>(
      fc6P, (size_t)MPAD * 4096, 4, fc6_b, POST_NMS_K, 4096, nullptr, fc6bf, 1);
  // 8. fc7: bf16 MFMA, split-K=2, epilogue in-place -> fp32
  gemm_mfma<<<dim3(64, MPAD / 64, 2), 256, 0, stream>>>(
      fc6bf, fc7_w, fc7P, 4096, 4096, 4096 / 32 / 2, (size_t)MPAD * 4096);
  epilogue_k<<<(POST_NMS_K * 4096 + 255) / 256, 256, 0, stream>>>(
      fc7P, (size_t)MPAD * 4096, 2, fc7_b, POST_NMS_K, 4096, fc7o, nullptr, 1);
  // 9. heads (fp32)
  gemv_nt<<<(POST_NMS_K * 32 + 255) / 256, 256, 0, stream>>>(fc7o, sfc_w, sfc_b, clsfc, POST_NMS_K, 32, 4096, 0);
  softmax32<<<(POST_NMS_K + 63) / 64, 64, 0, stream>>>(clsfc, out);
  gemv_nt<<<(POST_NMS_K * 128 + 255) / 256, 256, 0, stream>>>(fc7o, bfc_w, bfc_b, out + 9600, POST_NMS_K, 128, 4096, 0);
}

// Round 3
// 2536.690 us; speedup vs baseline: 1.4039x; 1.1019x over previous
//
#include <hip/hip_runtime.h>
#include <cstdint>
#include <cstddef>

// ---------------- problem constants ----------------
#define H_FEAT 38
#define W_FEAT 63
#define NPIX   2394        // 38*63
#define NANCH  21546       // NPIX*9
#define NSORT  32768       // next pow2 >= NANCH
#define PRE_NMS_K 6000
#define POST_NMS_K 300
#define KCONV  4608        // 512*9
#define NMS_TH 0.7f
#define MPAD   320         // fc6/fc7 padded M
#define NW64   94          // ceil(6000/64) words of suppression bitmask
#define NPAD   6016        // NW64*64

typedef __bf16 bf16_t;
typedef bf16_t bf16x8 __attribute__((ext_vector_type(8)));
typedef float  f32x4  __attribute__((ext_vector_type(4)));

// packed fragment-major layout: elem (row,k) of a [R x K] matrix ->
// group = (k/32)*RT + row/16 ; within group: (row%16)*32 + ((k/8)%4)*8 + k%8
// one 16-row x 32-k tile = 512 elems = 1KB bf16 = exactly one wave's bf16x8 load.
__device__ __forceinline__ size_t packed_off(int row, int k, int RT) {
  return ((size_t)(k >> 5) * RT + (row >> 4)) * 512 +
         (size_t)(((row & 15) << 5) + (((k >> 3) & 3) << 3) + (k & 7));
}

// canonical Faster-RCNN anchors (base 16, ratios .5/1/2, scales 8/16/32)
__device__ const float ANCHORS[9][4] = {
  { -84.f, -40.f,  99.f,  55.f}, {-176.f, -88.f, 191.f, 103.f}, {-360.f,-184.f, 375.f, 199.f},
  { -56.f, -56.f,  71.f,  71.f}, {-120.f,-120.f, 135.f, 135.f}, {-248.f,-248.f, 263.f, 263.f},
  { -36.f, -80.f,  51.f,  95.f}, { -80.f,-168.f,  95.f, 183.f}, {-168.f,-344.f, 183.f, 359.f}};

// ================= fp32 tiled NT GEMM (RPN conv only — selection path stays fp32) ==========
#define BM 64
#define BN 64
#define BK 16

template<int AMODE>
__launch_bounds__(256)
__global__ void gemm_nt(const float* __restrict__ A, const float* __restrict__ W,
                        const float* __restrict__ bias, float* __restrict__ C,
                        int M, int N, int K, int relu) {
  __shared__ float As[BK][BM];
  __shared__ float Bs[BK][BN];
  const int tid = threadIdx.x;
  const int m0 = blockIdx.y * BM;
  const int n0 = blockIdx.x * BN;
  const int lr = tid >> 2;          // 0..63 tile row
  const int lk = (tid & 3) * 4;     // k offset within BK
  const int ty = tid >> 4, tx = tid & 15;
  const int gm = m0 + lr;
  const int ph = gm / W_FEAT, pw = gm - (gm / W_FEAT) * W_FEAT;

  auto loadA = [&](int k0) -> float4 {
    if (AMODE == 0) {
      return (gm < M) ? *(const float4*)(A + (size_t)gm * K + k0 + lk)
                      : make_float4(0.f, 0.f, 0.f, 0.f);
    } else {
      float t[4];
      if (gm < M) {
#pragma unroll
        for (int q = 0; q < 4; ++q) {
          int k = k0 + lk + q;
          int ic = k / 9, tap = k - ic * 9;
          int hh = ph + tap / 3 - 1, ww = pw + (tap % 3) - 1;
          t[q] = (hh >= 0 && hh < H_FEAT && ww >= 0 && ww < W_FEAT)
                   ? A[(ic * H_FEAT + hh) * W_FEAT + ww] : 0.f;
        }
      } else { t[0] = t[1] = t[2] = t[3] = 0.f; }
      return make_float4(t[0], t[1], t[2], t[3]);
    }
  };
  auto loadB = [&](int k0) -> float4 {
    return *(const float4*)(W + (size_t)(n0 + lr) * K + k0 + lk);
  };

  float acc[4][4] = {};
  float4 av = loadA(0), bv = loadB(0);
  for (int k0 = 0; k0 < K; k0 += BK) {
    __syncthreads();
    As[lk + 0][lr] = av.x; As[lk + 1][lr] = av.y; As[lk + 2][lr] = av.z; As[lk + 3][lr] = av.w;
    Bs[lk + 0][lr] = bv.x; Bs[lk + 1][lr] = bv.y; Bs[lk + 2][lr] = bv.z; Bs[lk + 3][lr] = bv.w;
    __syncthreads();
    if (k0 + BK < K) { av = loadA(k0 + BK); bv = loadB(k0 + BK); }
#pragma unroll
    for (int kk = 0; kk < BK; ++kk) {
      float4 a = *(const float4*)&As[kk][ty * 4];
      float4 b = *(const float4*)&Bs[kk][tx * 4];
      float ar[4] = {a.x, a.y, a.z, a.w}, br[4] = {b.x, b.y, b.z, b.w};
#pragma unroll
      for (int i = 0; i < 4; ++i)
#pragma unroll
        for (int j = 0; j < 4; ++j) acc[i][j] += ar[i] * br[j];
    }
  }
  float4 bb = *(const float4*)(bias + n0 + tx * 4);
  float bb4[4] = {bb.x, bb.y, bb.z, bb.w};
#pragma unroll
  for (int i = 0; i < 4; ++i) {
    int om = m0 + ty * 4 + i;
    if (om < M) {
      float o[4];
#pragma unroll
      for (int j = 0; j < 4; ++j) {
        o[j] = acc[i][j] + bb4[j];
        if (relu) o[j] = fmaxf(o[j], 0.f);
      }
      *(float4*)(C + (size_t)om * N + n0 + tx * 4) = make_float4(o[0], o[1], o[2], o[3]);
    }
  }
}

// ================= W fp32 -> packed bf16 converter (RT fixed = 256 row-tiles) ==========
__global__ void pack_w_bf16(const float* __restrict__ W, bf16_t* __restrict__ P,
                            int K, int total) {
  int gid = blockIdx.x * blockDim.x + threadIdx.x;
  if (gid >= total) return;
  int q = gid & 3;
  int t = gid >> 2;
  int l = t & 15; t >>= 4;
  int rt = t & 255;          // RT = 256 (N=4096)
  int ks = t >> 8;
  int row = (rt << 4) | l;
  int k = (ks << 5) + (q << 3);
  const float* src = W + (size_t)row * K + k;
  f32x4 va = *(const f32x4*)src;
  f32x4 vb = *(const f32x4*)(src + 4);
  bf16x8 o;
#pragma unroll
  for (int j = 0; j < 4; ++j) { o[j] = (bf16_t)va[j]; o[j + 4] = (bf16_t)vb[j]; }
  *(bf16x8*)(P + (size_t)gid * 8) = o;
}

// ================= packed-operand bf16 MFMA GEMM (split-K) ==========
// Every load is one bf16x8 per lane covering exactly 1KB contiguous per wave.
__launch_bounds__(256)
__global__ void gemm_mfma_p(const bf16_t* __restrict__ Ap, const bf16_t* __restrict__ Wp,
                            float* __restrict__ Cp, int MT, int NT, int N, int kSteps,
                            size_t sliceElems) {
  const int tid = threadIdx.x;
  const int wave = tid >> 6, lane = tid & 63;
  const int l15 = lane & 15, quad = lane >> 4;
  const int wm = wave & 1, wn = wave >> 1;
  const int m0 = blockIdx.y * 64 + wm * 32;
  const int n0 = blockIdx.x * 64 + wn * 32;
  const int z = blockIdx.z;
  const int ks0 = z * kSteps;

  const size_t lofs = (size_t)((l15 << 5) + (quad << 3));
  const bf16_t* a0 = Ap + ((size_t)ks0 * MT + (m0 >> 4)) * 512 + lofs;
  const bf16_t* w0 = Wp + ((size_t)ks0 * NT + (n0 >> 4)) * 512 + lofs;
  const size_t strideA = (size_t)MT * 512, strideW = (size_t)NT * 512;

  f32x4 acc00 = {0.f, 0.f, 0.f, 0.f}, acc01 = acc00, acc10 = acc00, acc11 = acc00;

  for (int ks = 0; ks < kSteps; ++ks) {
    bf16x8 af0 = *(const bf16x8*)a0;
    bf16x8 af1 = *(const bf16x8*)(a0 + 512);
    bf16x8 bf0 = *(const bf16x8*)w0;
    bf16x8 bf1 = *(const bf16x8*)(w0 + 512);
    acc00 = __builtin_amdgcn_mfma_f32_16x16x32_bf16(af0, bf0, acc00, 0, 0, 0);
    acc01 = __builtin_amdgcn_mfma_f32_16x16x32_bf16(af0, bf1, acc01, 0, 0, 0);
    acc10 = __builtin_amdgcn_mfma_f32_16x16x32_bf16(af1, bf0, acc10, 0, 0, 0);
    acc11 = __builtin_amdgcn_mfma_f32_16x16x32_bf16(af1, bf1, acc11, 0, 0, 0);
    a0 += strideA; w0 += strideW;
  }

  // C/D layout (m89-verified): col = lane&15, row = quad*4 + reg
  float* Cz = Cp + (size_t)z * sliceElems;
  const int rb = m0 + quad * 4;
#pragma unroll
  for (int i = 0; i < 4; ++i) {
    Cz[(size_t)(rb + i) * N + n0 + l15]           = acc00[i];
    Cz[(size_t)(rb + i) * N + n0 + 16 + l15]      = acc01[i];
    Cz[(size_t)(rb + 16 + i) * N + n0 + l15]      = acc10[i];
    Cz[(size_t)(rb + 16 + i) * N + n0 + 16 + l15] = acc11[i];
  }
}

// ================= legacy bf16 MFMA GEMM (fallback when ws too small for packed W) ======
__launch_bounds__(256)
__global__ void gemm_mfma(const bf16_t* __restrict__ A, const float* __restrict__ Wt,
                          float* __restrict__ Cp, int K, int N, int kSteps,
                          size_t sliceElems) {
  const int tid = threadIdx.x;
  const int wave = tid >> 6, lane = tid & 63;
  const int l15 = lane & 15, quad = lane >> 4;
  const int wm = wave & 1, wn = wave >> 1;
  const int m0 = blockIdx.y * 64 + wm * 32;
  const int n0 = blockIdx.x * 64 + wn * 32;
  const int z = blockIdx.z;
  const int kb = z * kSteps * 32;

  const bf16_t* a0 = A + (size_t)(m0 + l15) * K + kb + quad * 8;
  const bf16_t* a1 = a0 + (size_t)16 * K;
  const float*  w0 = Wt + (size_t)(n0 + l15) * K + kb + quad * 8;
  const float*  w1 = w0 + (size_t)16 * K;

  f32x4 acc00 = {0.f, 0.f, 0.f, 0.f}, acc01 = acc00, acc10 = acc00, acc11 = acc00;

  for (int ks = 0; ks < kSteps; ++ks) {
    bf16x8 af0 = *(const bf16x8*)a0;
    bf16x8 af1 = *(const bf16x8*)a1;
    f32x4 b0a = *(const f32x4*)w0;
    f32x4 b0b = *(const f32x4*)(w0 + 4);
    f32x4 b1a = *(const f32x4*)w1;
    f32x4 b1b = *(const f32x4*)(w1 + 4);
    bf16x8 bf0, bf1;
#pragma unroll
    for (int j = 0; j < 4; ++j) {
      bf0[j] = (bf16_t)b0a[j]; bf0[j + 4] = (bf16_t)b0b[j];
      bf1[j] = (bf16_t)b1a[j]; bf1[j + 4] = (bf16_t)b1b[j];
    }
    acc00 = __builtin_amdgcn_mfma_f32_16x16x32_bf16(af0, bf0, acc00, 0, 0, 0);
    acc01 = __builtin_amdgcn_mfma_f32_16x16x32_bf16(af0, bf1, acc01, 0, 0, 0);
    acc10 = __builtin_amdgcn_mfma_f32_16x16x32_bf16(af1, bf0, acc10, 0, 0, 0);
    acc11 = __builtin_amdgcn_mfma_f32_16x16x32_bf16(af1, bf1, acc11, 0, 0, 0);
    a0 += 32; a1 += 32; w0 += 32; w1 += 32;
  }

  float* Cz = Cp + (size_t)z * sliceElems;
  const int rb = m0 + quad * 4;
#pragma unroll
  for (int i = 0; i < 4; ++i) {
    Cz[(size_t)(rb + i) * N + n0 + l15]           = acc00[i];
    Cz[(size_t)(rb + i) * N + n0 + 16 + l15]      = acc01[i];
    Cz[(size_t)(rb + 16 + i) * N + n0 + l15]      = acc10[i];
    Cz[(size_t)(rb + 16 + i) * N + n0 + 16 + l15] = acc11[i];
  }
}

// reduce split-K partials + bias + relu; optional fp32 and/or bf16 outputs.
// packB: bf16 output written in packed fragment-major layout (RT = MPAD/16 = 20).
__global__ void epilogue_k(const float* __restrict__ Cp, size_t sliceElems, int KS,
                           const float* __restrict__ bias, int M, int N,
                           float* __restrict__ out_f32, bf16_t* __restrict__ out_bf16,
                           int relu, int packB) {
  int idx = blockIdx.x * blockDim.x + threadIdx.x;
  if (idx >= M * N) return;
  int m = idx / N, n = idx - m * N;
  float s = 0.f;
  for (int z = 0; z < KS; ++z) s += Cp[(size_t)z * sliceElems + idx];
  s += bias[n];
  if (relu) s = fmaxf(s, 0.f);
  if (out_f32)  out_f32[idx] = s;
  if (out_bf16) {
    size_t o = packB ? packed_off(m, n, MPAD / 16) : (size_t)idx;
    out_bf16[o] = (bf16_t)s;
  }
}

// ---------------- small-N GEMM: one thread per C element ----------------
__global__ void gemv_nt(const float* __restrict__ A, const float* __restrict__ W,
                        const float* __restrict__ bias, float* __restrict__ C,
                        int M, int N, int K, int relu) {
  int gid = blockIdx.x * blockDim.x + threadIdx.x;
  if (gid >= M * N) return;
  int m = gid / N, n = gid - m * N;
  const float* a = A + (size_t)m * K;
  const float* w = W + (size_t)n * K;
  float acc = 0.f;
  for (int k = 0; k < K; k += 4) {
    float4 x = *(const float4*)(a + k);
    float4 y = *(const float4*)(w + k);
    acc += x.x * y.x + x.y * y.y + x.z * y.z + x.w * y.w;
  }
  float o = acc + bias[n];
  if (relu) o = fmaxf(o, 0.f);
  C[gid] = o;
}

// ---------------- proposal prep: scores, boxes, sort keys ----------------
__device__ inline unsigned flip_f32(float f) {
  unsigned u = __float_as_uint(f);
  return (u & 0x80000000u) ? ~u : (u | 0x80000000u);
}

__global__ void proposal_prep(const float* __restrict__ cls,
                              const float* __restrict__ bbox,
                              const float* __restrict__ info,
                              float* __restrict__ props,
                              float* __restrict__ scores,
                              unsigned long long* __restrict__ keys) {
  int idx = blockIdx.x * blockDim.x + threadIdx.x;
  if (idx >= NSORT) return;
  unsigned long long key = 0ull;
  if (idx < NANCH) {
    int a = idx % 9, m = idx / 9;
    int h = m / W_FEAT, w = m - (m / W_FEAT) * W_FEAT;
    float s0 = cls[m * 18 + a], s1 = cls[m * 18 + 9 + a];
    float mx = fmaxf(s0, s1);
    float e0 = expf(s0 - mx), e1 = expf(s1 - mx);
    float sc = e1 / (e0 + e1);
    const float* d = bbox + m * 36 + a * 4;
    float dx = d[0], dy = d[1], dw = d[2], dh = d[3];
    float ax1 = ANCHORS[a][0] + w * 16.f, ay1 = ANCHORS[a][1] + h * 16.f;
    float ax2 = ANCHORS[a][2] + w * 16.f, ay2 = ANCHORS[a][3] + h * 16.f;
    float aw = ax2 - ax1 + 1.f, ah = ay2 - ay1 + 1.f;
    float cx = ax1 + 0.5f * aw, cy = ay1 + 0.5f * ah;
    float pcx = dx * aw + cx, pcy = dy * ah + cy;
    float pww = expf(dw) * aw, phh = expf(dh) * ah;
    float x1 = pcx - 0.5f * pww, y1 = pcy - 0.5f * phh;
    float x2 = pcx + 0.5f * pww, y2 = pcy + 0.5f * phh;
    float imh = info[0], imw = info[1], iscale = info[2];
    x1 = fminf(fmaxf(x1, 0.f), imw - 1.f);
    y1 = fminf(fmaxf(y1, 0.f), imh - 1.f);
    x2 = fminf(fmaxf(x2, 0.f), imw - 1.f);
    y2 = fminf(fmaxf(y2, 0.f), imh - 1.f);
    bool ok = (x2 - x1 + 1.f >= 16.f * iscale) && (y2 - y1 + 1.f >= 16.f * iscale);
    float s = ok ? sc : -INFINITY;
    *(float4*)(props + 4 * idx) = make_float4(x1, y1, x2, y2);
    scores[idx] = s;
    key = ((unsigned long long)flip_f32(s) << 32) |
          (unsigned long long)(0xFFFFFFFFu - (unsigned)idx);
  }
  keys[idx] = key;
}

// ---------------- bitonic sort (descending), 32768 u64 keys ----------------
__global__ void bitonic_global(unsigned long long* __restrict__ keys, int j, int k) {
  int i = blockIdx.x * blockDim.x + threadIdx.x;
  int l = i ^ j;
  if (l > i) {
    unsigned long long a = keys[i], b = keys[l];
    bool up = ((i & k) == 0);
    if (up ? (a < b) : (a > b)) { keys[i] = b; keys[l] = a; }
  }
}

__launch_bounds__(1024)
__global__ void bitonic_lds(unsigned long long* __restrict__ keys, int jstart, int k) {
  __shared__ unsigned long long s[2048];
  const int tid = threadIdx.x;
  const int base = blockIdx.x * 2048;
  s[tid] = keys[base + tid];
  s[tid + 1024] = keys[base + tid + 1024];
  __syncthreads();
  for (int j = jstart; j > 0; j >>= 1) {
    int il = ((tid & ~(j - 1)) << 1) | (tid & (j - 1));
    int ig = base + il;
    bool up = ((ig & k) == 0);
    unsigned long long a = s[il], b = s[il + j];
    if (up ? (a < b) : (a > b)) { s[il] = b; s[il + j] = a; }
    __syncthreads();
  }
  keys[base + tid] = s[tid];
  keys[base + tid + 1024] = s[tid + 1024];
}

// ================= NMS: parallel IoU bitmask + single-wave greedy scan ==========
__global__ void nms_gather(const unsigned long long* __restrict__ keys,
                           const float* __restrict__ props,
                           const float* __restrict__ scores,
                           float4* __restrict__ sbox, float* __restrict__ sarea,
                           float* __restrict__ sscore,
                           unsigned long long* __restrict__ vmask) {
  int j = blockIdx.x * blockDim.x + threadIdx.x;
  bool valid = false;
  float4 b = make_float4(0.f, 0.f, 0.f, 0.f);
  float s = -INFINITY, area = 0.f;
  if (j < PRE_NMS_K) {
    unsigned long long k = keys[j];
    unsigned orig = 0xFFFFFFFFu - (unsigned)(k & 0xFFFFFFFFull);
    b = *(const float4*)(props + 4 * (size_t)orig);
    s = scores[orig];
    area = (b.z - b.x + 1.f) * (b.w - b.y + 1.f);
    valid = (s != -INFINITY);
  }
  if (j < NPAD) { sbox[j] = b; sarea[j] = area; sscore[j] = s; }
  unsigned long long ball = __ballot(valid);
  if ((threadIdx.x & 63) == 0 && j < NPAD) vmask[j >> 6] = ball;
}

__global__ void nms_mask(const float4* __restrict__ sbox, const float* __restrict__ sarea,
                         unsigned long long* __restrict__ mask) {
  int idx = blockIdx.x * blockDim.x + threadIdx.x;
  if (idx >= NPAD * NW64) return;
  int j = idx / NW64, w = idx - j * NW64;
  float4 bj = sbox[j];
  float aj = sarea[j];
  unsigned long long m = 0ull;
  int kbase = w * 64;
#pragma unroll 8
  for (int b = 0; b < 64; ++b) {
    int k = kbase + b;
    float4 bk = sbox[k];
    float xx1 = fmaxf(bj.x, bk.x), yy1 = fmaxf(bj.y, bk.y);
    float xx2 = fminf(bj.z, bk.z), yy2 = fminf(bj.w, bk.w);
    float iw = fmaxf(xx2 - xx1 + 1.f, 0.f), ih = fmaxf(yy2 - yy1 + 1.f, 0.f);
    float inter = iw * ih;
    float iou = inter / (aj + sarea[k] - inter);
    if (iou > NMS_TH) m |= (1ull << b);
  }
  mask[(size_t)j * NW64 + w] = m;
}

__launch_bounds__(64)
__global__ void nms_scan(const float4* __restrict__ sbox,
                         const unsigned long long* __restrict__ vmask,
                         const unsigned long long* __restrict__ mask,
                         float* __restrict__ rois_out) {
  const int lane = threadIdx.x;
  const int w0 = 2 * lane, w1 = 2 * lane + 1;
  unsigned long long S0 = 0ull, S1 = 0ull;
  const unsigned long long V0 = (w0 < NW64) ? vmask[w0] : 0ull;
  const unsigned long long V1 = (w1 < NW64) ? vmask[w1] : 0ull;
  __shared__ int keepIdx[POST_NMS_K];
  int keeps = 0;
  for (int w = 0; w < NW64 && keeps < POST_NMS_K; ++w) {
    const int owner = w >> 1;
    unsigned long long candsrc = (w & 1) ? ((~S1) & V1) : ((~S0) & V0);
    unsigned long long cw = __shfl(candsrc, owner);
    while (cw) {
      int b = __builtin_ctzll(cw);
      int j = w * 64 + b;
      if (lane == 0) keepIdx[keeps] = j;
      keeps++;
      if (keeps == POST_NMS_K) break;
      const unsigned long long* row = mask + (size_t)j * NW64;
      if (w0 < NW64) S0 |= row[w0];
      if (w1 < NW64) S1 |= row[w1];
      candsrc = (w & 1) ? ((~S1) & V1) : ((~S0) & V0);
      unsigned long long hi = (b == 63) ? 0ull : (~0ull << (b + 1));
      cw = __shfl(candsrc, owner) & hi;
    }
  }
  __syncthreads();
  for (int t = lane; t < POST_NMS_K; t += 64) {
    int j = (t < keeps) ? keepIdx[t] : 0;
    float4 bx = sbox[j];
    *(float4*)(rois_out + 4 * t) = bx;
  }
}

// ---------------- ROI max pooling -> bf16 (PACK: fragment-major output) ----------------
template<int PACK>
__global__ void roi_pool(const float* __restrict__ feat,
                         const float* __restrict__ rois,
                         bf16_t* __restrict__ out) {
  const int r = blockIdx.x;
  const float4 roi = *(const float4*)(rois + 4 * r);
  float rsw = rintf(roi.x * 0.0625f);
  float rsh = rintf(roi.y * 0.0625f);
  float rew = rintf(roi.z * 0.0625f);
  float reh = rintf(roi.w * 0.0625f);
  float bw = fmaxf(rew - rsw + 1.f, 1.f) / 7.f;
  float bh = fmaxf(reh - rsh + 1.f, 1.f) / 7.f;
  for (int idx = threadIdx.x; idx < 512 * 49; idx += blockDim.x) {
    int c = idx / 49, b = idx - c * 49;
    int ph = b / 7, pw = b - ph * 7;
    float hs = fminf(fmaxf(floorf(ph * bh) + rsh, 0.f), (float)H_FEAT);
    float he = fminf(fmaxf(ceilf((ph + 1) * bh) + rsh, 0.f), (float)H_FEAT);
    float wS = fminf(fmaxf(floorf(pw * bw) + rsw, 0.f), (float)W_FEAT);
    float wE = fminf(fmaxf(ceilf((pw + 1) * bw) + rsw, 0.f), (float)W_FEAT);
    int h0 = (int)hs, h1 = (int)he, w0 = (int)wS, w1 = (int)wE;
    float m = -1e30f;
    const float* fc = feat + (size_t)c * (H_FEAT * W_FEAT);
    for (int h = h0; h < h1; ++h)
      for (int w = w0; w < w1; ++w)
        m = fmaxf(m, fc[h * W_FEAT + w]);
    size_t o = PACK ? packed_off(r, idx, MPAD / 16) : ((size_t)r * 25088 + idx);
    out[o] = (bf16_t)((m < -1e29f) ? 0.f : m);
  }
}

// ---------------- row softmax (300 x 32) ----------------
__global__ void softmax32(const float* __restrict__ in, float* __restrict__ out) {
  int r = blockIdx.x * blockDim.x + threadIdx.x;
  if (r >= POST_NMS_K) return;
  const float* x = in + r * 32;
  float m = x[0];
#pragma unroll
  for (int k = 1; k < 32; ++k) m = fmaxf(m, x[k]);
  float e[32]; float s = 0.f;
#pragma unroll
  for (int k = 0; k < 32; ++k) { e[k] = expf(x[k] - m); s += e[k]; }
  float inv = 1.f / s;
#pragma unroll
  for (int k = 0; k < 32; ++k) out[r * 32 + k] = e[k] * inv;
}

// ---------------- launch ----------------
extern "C" void kernel_launch(void* const* d_in, const int* in_sizes, int n_in,
                              void* d_out, int out_size, void* d_ws, size_t ws_size,
                              hipStream_t stream) {
  const float* feat    = (const float*)d_in[0];
  const float* info    = (const float*)d_in[1];
  const float* conv1_w = (const float*)d_in[2];
  const float* conv1_b = (const float*)d_in[3];
  const float* score_w = (const float*)d_in[4];
  const float* score_b = (const float*)d_in[5];
  const float* bbox_w  = (const float*)d_in[6];
  const float* bbox_b  = (const float*)d_in[7];
  const float* fc6_w   = (const float*)d_in[8];
  const float* fc6_b   = (const float*)d_in[9];
  const float* fc7_w   = (const float*)d_in[10];
  const float* fc7_b   = (const float*)d_in[11];
  const float* sfc_w   = (const float*)d_in[12];
  const float* sfc_b   = (const float*)d_in[13];
  const float* bfc_w   = (const float*)d_in[14];
  const float* bfc_b   = (const float*)d_in[15];
  float* out = (float*)d_out;
  char*  ws  = (char*)d_ws;

  size_t off = 0;
  auto alloc = [&](size_t bytes) { size_t o = off; off += (bytes + 255) & ~(size_t)255; return o; };
  float* cls    = (float*)(ws + alloc((size_t)NPIX * 18 * 4));
  float* bbx    = (float*)(ws + alloc((size_t)NPIX * 36 * 4));
  float* props  = (float*)(ws + alloc((size_t)NANCH * 4 * 4));
  float* scores = (float*)(ws + alloc((size_t)NANCH * 4));
  unsigned long long* keys = (unsigned long long*)(ws + alloc((size_t)NSORT * 8));
  float* rpn    = (float*)(ws + alloc((size_t)NPIX * 512 * 4));
  // pooled region (bf16, 320x25088 = 16.06MB) is dead after fc6 GEMM; fc7 partials overlay it.
  char*  pooled_raw = ws + alloc((size_t)MPAD * 25088 * 2);
  bf16_t* pooled = (bf16_t*)pooled_raw;
  float*  fc7P   = (float*)pooled_raw;                 // 2 x 320*4096*4 = 10.49MB  (overlay)
  float*  fc7o   = fc7P;                               // epilogue in-place on slice 0
  float* fc6P    = (float*)(ws + alloc((size_t)4 * MPAD * 4096 * 4));
  bf16_t* fc6bf  = (bf16_t*)(ws + alloc((size_t)MPAD * 4096 * 2));
  float* clsfc   = (float*)(ws + alloc((size_t)POST_NMS_K * 32 * 4));

  // NMS scratch overlays fc6P (21.5MB; dead until fc6 GEMM which launches after nms_scan)
  char* nmsbase = (char*)fc6P;
  float4* sbox  = (float4*)nmsbase;
  float*  sarea = (float*)(nmsbase + 96256);
  float*  sscore= (float*)(nmsbase + 120320);
  unsigned long long* vmask = (unsigned long long*)(nmsbase + 144384);
  unsigned long long* maskb = (unsigned long long*)(nmsbase + 145408);

  // packed bf16 weights (allocated LAST so fallback layout matches legacy exactly)
  bf16_t* fc6wp = (bf16_t*)(ws + alloc((size_t)4096 * 25088 * 2));  // 205.5MB
  bf16_t* fc7wp = (bf16_t*)(ws + alloc((size_t)4096 * 4096 * 2));   //  33.6MB
  const bool packed = (off <= ws_size);

  float* rois_out = out + 9600 + 38400;   // cls_prob(300x32) | box(300x128) | rois(300x4)

  // 1. RPN conv 3x3 + relu (fp32 — selection path must stay bit-stable)
  gemm_nt<1><<<dim3(512 / BN, (NPIX + BM - 1) / BM), 256, 0, stream>>>(
      feat, conv1_w, conv1_b, rpn, NPIX, 512, KCONV, 1);
  // 2. 1x1 convs (fp32)
  gemv_nt<<<(NPIX * 18 + 255) / 256, 256, 0, stream>>>(rpn, score_w, score_b, cls, NPIX, 18, 512, 0);
  gemv_nt<<<(NPIX * 36 + 255) / 256, 256, 0, stream>>>(rpn, bbox_w, bbox_b, bbx, NPIX, 36, 512, 0);
  // 3. proposals + sort keys
  proposal_prep<<<NSORT / 256, 256, 0, stream>>>(cls, bbx, info, props, scores, keys);
  // 4. bitonic sort, descending
  for (int k = 2; k <= 2048; k <<= 1)
    bitonic_lds<<<NSORT / 2048, 1024, 0, stream>>>(keys, k >> 1, k);
  for (int k = 4096; k <= NSORT; k <<= 1) {
    for (int j = k >> 1; j >= 2048; j >>= 1)
      bitonic_global<<<NSORT / 256, 256, 0, stream>>>(keys, j, k);
    bitonic_lds<<<NSORT / 2048, 1024, 0, stream>>>(keys, 1024, k);
  }
  // 5. NMS: gather -> parallel IoU bitmask -> single-wave greedy scan
  nms_gather<<<(NPAD + 255) / 256, 256, 0, stream>>>(keys, props, scores, sbox, sarea, sscore, vmask);
  nms_mask<<<(NPAD * NW64 + 255) / 256, 256, 0, stream>>>(sbox, sarea, maskb);
  nms_scan<<<1, 64, 0, stream>>>(sbox, vmask, maskb, rois_out);

  if (packed) {
    // 6. weight repack (streaming, coalesced) + ROI pool into packed layout
    pack_w_bf16<<<(4096 * 25088 / 8) / 256, 256, 0, stream>>>(fc6_w, fc6wp, 25088, 4096 * 25088 / 8);
    pack_w_bf16<<<(4096 * 4096 / 8) / 256, 256, 0, stream>>>(fc7_w, fc7wp, 4096, 4096 * 4096 / 8);
    roi_pool<1><<<POST_NMS_K, 256, 0, stream>>>(feat, rois_out, pooled);
    // 7. fc6: packed bf16 MFMA, split-K=4, then reduce+bias+relu -> packed bf16
    gemm_mfma_p<<<dim3(64, MPAD / 64, 4), 256, 0, stream>>>(
        pooled, fc6wp, fc6P, MPAD / 16, 256, 4096, 25088 / 32 / 4, (size_t)MPAD * 4096);
    epilogue_k<<<(POST_NMS_K * 4096 + 255) / 256, 256, 0, stream>>>(
        fc6P, (size_t)MPAD * 4096, 4, fc6_b, POST_NMS_K, 4096, nullptr, fc6bf, 1, 1);
    // 8. fc7: packed bf16 MFMA, split-K=2, epilogue in-place -> fp32
    gemm_mfma_p<<<dim3(64, MPAD / 64, 2), 256, 0, stream>>>(
        fc6bf, fc7wp, fc7P, MPAD / 16, 256, 4096, 4096 / 32 / 2, (size_t)MPAD * 4096);
    epilogue_k<<<(POST_NMS_K * 4096 + 255) / 256, 256, 0, stream>>>(
        fc7P, (size_t)MPAD * 4096, 2, fc7_b, POST_NMS_K, 4096, fc7o, nullptr, 1, 0);
  } else {
    // fallback: legacy path (fp32 W converted in-reg)
    roi_pool<0><<<POST_NMS_K, 256, 0, stream>>>(feat, rois_out, pooled);
    gemm_mfma<<<dim3(64, MPAD / 64, 4), 256, 0, stream>>>(
        pooled, fc6_w, fc6P, 25088, 4096, 25088 / 32 / 4, (size_t)MPAD * 4096);
    epilogue_k<<<(POST_NMS_K * 4096 + 255) / 256, 256, 0, stream>>>(
        fc6P, (size_t)MPAD * 4096, 4, fc6_b, POST_NMS_K, 4096, nullptr, fc6bf, 1, 0);
    gemm_mfma<<<dim3(64, MPAD / 64, 2), 256, 0, stream>>>(
        fc6bf, fc7_w, fc7P, 4096, 4096, 4096 / 32 / 2, (size_t)MPAD * 4096);
    epilogue_k<<<(POST_NMS_K * 4096 + 255) / 256, 256, 0, stream>>>(
        fc7P, (size_t)MPAD * 4096, 2, fc7_b, POST_NMS_K, 4096, fc7o, nullptr, 1, 0);
  }
  // 9. heads (fp32)
  gemv_nt<<<(POST_NMS_K * 32 + 255) / 256, 256, 0, stream>>>(fc7o, sfc_w, sfc_b, clsfc, POST_NMS_K, 32, 4096, 0);
  softmax32<<<(POST_NMS_K + 63) / 64, 64, 0, stream>>>(clsfc, out);
  gemv_nt<<<(POST_NMS_K * 128 + 255) / 256, 256, 0, stream>>>(fc7o, bfc_w, bfc_b, out + 9600, POST_NMS_K, 128, 4096, 0);
}

// Round 4
// 2166.438 us; speedup vs baseline: 1.6439x; 1.1709x over previous
//
#include <hip/hip_runtime.h>
#include <cstdint>
#include <cstddef>

// ---------------- problem constants ----------------
#define H_FEAT 38
#define W_FEAT 63
#define NPIX   2394        // 38*63
#define NANCH  21546       // NPIX*9
#define NSORT  32768       // next pow2 >= NANCH
#define PRE_NMS_K 6000
#define POST_NMS_K 300
#define KCONV  4608        // 512*9
#define NMS_TH 0.7f
#define MPAD   320         // fc6/fc7 padded M
#define NW64   94          // ceil(6000/64) words of suppression bitmask
#define NPAD   6016        // NW64*64

typedef __bf16 bf16_t;
typedef bf16_t bf16x8 __attribute__((ext_vector_type(8)));
typedef float  f32x4  __attribute__((ext_vector_type(4)));

// packed fragment-major layout: elem (row,k) of a [R x K] matrix ->
// group = (k/32)*RT + row/16 ; within group: (row%16)*32 + ((k/8)%4)*8 + k%8
// one 16-row x 32-k tile = 512 elems = 1KB bf16 = exactly one wave's bf16x8 load.
__device__ __forceinline__ size_t packed_off(int row, int k, int RT) {
  return ((size_t)(k >> 5) * RT + (row >> 4)) * 512 +
         (size_t)(((row & 15) << 5) + (((k >> 3) & 3) << 3) + (k & 7));
}

// canonical Faster-RCNN anchors (base 16, ratios .5/1/2, scales 8/16/32)
__device__ const float ANCHORS[9][4] = {
  { -84.f, -40.f,  99.f,  55.f}, {-176.f, -88.f, 191.f, 103.f}, {-360.f,-184.f, 375.f, 199.f},
  { -56.f, -56.f,  71.f,  71.f}, {-120.f,-120.f, 135.f, 135.f}, {-248.f,-248.f, 263.f, 263.f},
  { -36.f, -80.f,  51.f,  95.f}, { -80.f,-168.f,  95.f, 183.f}, {-168.f,-344.f, 183.f, 359.f}};

// ================= fp32 tiled NT GEMM (RPN conv only — selection path stays fp32) ==========
#define BM 64
#define BN 64
#define BK 16

template<int AMODE>
__launch_bounds__(256)
__global__ void gemm_nt(const float* __restrict__ A, const float* __restrict__ W,
                        const float* __restrict__ bias, float* __restrict__ C,
                        int M, int N, int K, int relu) {
  __shared__ float As[BK][BM];
  __shared__ float Bs[BK][BN];
  const int tid = threadIdx.x;
  const int m0 = blockIdx.y * BM;
  const int n0 = blockIdx.x * BN;
  const int lr = tid >> 2;          // 0..63 tile row
  const int lk = (tid & 3) * 4;     // k offset within BK
  const int ty = tid >> 4, tx = tid & 15;
  const int gm = m0 + lr;
  const int ph = gm / W_FEAT, pw = gm - (gm / W_FEAT) * W_FEAT;

  auto loadA = [&](int k0) -> float4 {
    if (AMODE == 0) {
      return (gm < M) ? *(const float4*)(A + (size_t)gm * K + k0 + lk)
                      : make_float4(0.f, 0.f, 0.f, 0.f);
    } else {
      float t[4];
      if (gm < M) {
#pragma unroll
        for (int q = 0; q < 4; ++q) {
          int k = k0 + lk + q;
          int ic = k / 9, tap = k - ic * 9;
          int hh = ph + tap / 3 - 1, ww = pw + (tap % 3) - 1;
          t[q] = (hh >= 0 && hh < H_FEAT && ww >= 0 && ww < W_FEAT)
                   ? A[(ic * H_FEAT + hh) * W_FEAT + ww] : 0.f;
        }
      } else { t[0] = t[1] = t[2] = t[3] = 0.f; }
      return make_float4(t[0], t[1], t[2], t[3]);
    }
  };
  auto loadB = [&](int k0) -> float4 {
    return *(const float4*)(W + (size_t)(n0 + lr) * K + k0 + lk);
  };

  float acc[4][4] = {};
  float4 av = loadA(0), bv = loadB(0);
  for (int k0 = 0; k0 < K; k0 += BK) {
    __syncthreads();
    As[lk + 0][lr] = av.x; As[lk + 1][lr] = av.y; As[lk + 2][lr] = av.z; As[lk + 3][lr] = av.w;
    Bs[lk + 0][lr] = bv.x; Bs[lk + 1][lr] = bv.y; Bs[lk + 2][lr] = bv.z; Bs[lk + 3][lr] = bv.w;
    __syncthreads();
    if (k0 + BK < K) { av = loadA(k0 + BK); bv = loadB(k0 + BK); }
#pragma unroll
    for (int kk = 0; kk < BK; ++kk) {
      float4 a = *(const float4*)&As[kk][ty * 4];
      float4 b = *(const float4*)&Bs[kk][tx * 4];
      float ar[4] = {a.x, a.y, a.z, a.w}, br[4] = {b.x, b.y, b.z, b.w};
#pragma unroll
      for (int i = 0; i < 4; ++i)
#pragma unroll
        for (int j = 0; j < 4; ++j) acc[i][j] += ar[i] * br[j];
    }
  }
  float4 bb = *(const float4*)(bias + n0 + tx * 4);
  float bb4[4] = {bb.x, bb.y, bb.z, bb.w};
#pragma unroll
  for (int i = 0; i < 4; ++i) {
    int om = m0 + ty * 4 + i;
    if (om < M) {
      float o[4];
#pragma unroll
      for (int j = 0; j < 4; ++j) {
        o[j] = acc[i][j] + bb4[j];
        if (relu) o[j] = fmaxf(o[j], 0.f);
      }
      *(float4*)(C + (size_t)om * N + n0 + tx * 4) = make_float4(o[0], o[1], o[2], o[3]);
    }
  }
}

// ================= W fp32 -> packed bf16 converter (RT fixed = 256 row-tiles) ==========
__global__ void pack_w_bf16(const float* __restrict__ W, bf16_t* __restrict__ P,
                            int K, int total) {
  int gid = blockIdx.x * blockDim.x + threadIdx.x;
  if (gid >= total) return;
  int q = gid & 3;
  int t = gid >> 2;
  int l = t & 15; t >>= 4;
  int rt = t & 255;          // RT = 256 (N=4096)
  int ks = t >> 8;
  int row = (rt << 4) | l;
  int k = (ks << 5) + (q << 3);
  const float* src = W + (size_t)row * K + k;
  f32x4 va = *(const f32x4*)src;
  f32x4 vb = *(const f32x4*)(src + 4);
  bf16x8 o;
#pragma unroll
  for (int j = 0; j < 4; ++j) { o[j] = (bf16_t)va[j]; o[j + 4] = (bf16_t)vb[j]; }
  *(bf16x8*)(P + (size_t)gid * 8) = o;
}

// ================= packed-operand bf16 MFMA GEMM (split-K) ==========
__launch_bounds__(256)
__global__ void gemm_mfma_p(const bf16_t* __restrict__ Ap, const bf16_t* __restrict__ Wp,
                            float* __restrict__ Cp, int MT, int NT, int N, int kSteps,
                            size_t sliceElems) {
  const int tid = threadIdx.x;
  const int wave = tid >> 6, lane = tid & 63;
  const int l15 = lane & 15, quad = lane >> 4;
  const int wm = wave & 1, wn = wave >> 1;
  const int m0 = blockIdx.y * 64 + wm * 32;
  const int n0 = blockIdx.x * 64 + wn * 32;
  const int z = blockIdx.z;
  const int ks0 = z * kSteps;

  const size_t lofs = (size_t)((l15 << 5) + (quad << 3));
  const bf16_t* a0 = Ap + ((size_t)ks0 * MT + (m0 >> 4)) * 512 + lofs;
  const bf16_t* w0 = Wp + ((size_t)ks0 * NT + (n0 >> 4)) * 512 + lofs;
  const size_t strideA = (size_t)MT * 512, strideW = (size_t)NT * 512;

  f32x4 acc00 = {0.f, 0.f, 0.f, 0.f}, acc01 = acc00, acc10 = acc00, acc11 = acc00;

  for (int ks = 0; ks < kSteps; ++ks) {
    bf16x8 af0 = *(const bf16x8*)a0;
    bf16x8 af1 = *(const bf16x8*)(a0 + 512);
    bf16x8 bf0 = *(const bf16x8*)w0;
    bf16x8 bf1 = *(const bf16x8*)(w0 + 512);
    acc00 = __builtin_amdgcn_mfma_f32_16x16x32_bf16(af0, bf0, acc00, 0, 0, 0);
    acc01 = __builtin_amdgcn_mfma_f32_16x16x32_bf16(af0, bf1, acc01, 0, 0, 0);
    acc10 = __builtin_amdgcn_mfma_f32_16x16x32_bf16(af1, bf0, acc10, 0, 0, 0);
    acc11 = __builtin_amdgcn_mfma_f32_16x16x32_bf16(af1, bf1, acc11, 0, 0, 0);
    a0 += strideA; w0 += strideW;
  }

  // C/D layout (m89-verified): col = lane&15, row = quad*4 + reg
  float* Cz = Cp + (size_t)z * sliceElems;
  const int rb = m0 + quad * 4;
#pragma unroll
  for (int i = 0; i < 4; ++i) {
    Cz[(size_t)(rb + i) * N + n0 + l15]           = acc00[i];
    Cz[(size_t)(rb + i) * N + n0 + 16 + l15]      = acc01[i];
    Cz[(size_t)(rb + 16 + i) * N + n0 + l15]      = acc10[i];
    Cz[(size_t)(rb + 16 + i) * N + n0 + 16 + l15] = acc11[i];
  }
}

// ================= legacy bf16 MFMA GEMM (fallback when ws too small for packed W) ======
__launch_bounds__(256)
__global__ void gemm_mfma(const bf16_t* __restrict__ A, const float* __restrict__ Wt,
                          float* __restrict__ Cp, int K, int N, int kSteps,
                          size_t sliceElems) {
  const int tid = threadIdx.x;
  const int wave = tid >> 6, lane = tid & 63;
  const int l15 = lane & 15, quad = lane >> 4;
  const int wm = wave & 1, wn = wave >> 1;
  const int m0 = blockIdx.y * 64 + wm * 32;
  const int n0 = blockIdx.x * 64 + wn * 32;
  const int z = blockIdx.z;
  const int kb = z * kSteps * 32;

  const bf16_t* a0 = A + (size_t)(m0 + l15) * K + kb + quad * 8;
  const bf16_t* a1 = a0 + (size_t)16 * K;
  const float*  w0 = Wt + (size_t)(n0 + l15) * K + kb + quad * 8;
  const float*  w1 = w0 + (size_t)16 * K;

  f32x4 acc00 = {0.f, 0.f, 0.f, 0.f}, acc01 = acc00, acc10 = acc00, acc11 = acc00;

  for (int ks = 0; ks < kSteps; ++ks) {
    bf16x8 af0 = *(const bf16x8*)a0;
    bf16x8 af1 = *(const bf16x8*)a1;
    f32x4 b0a = *(const f32x4*)w0;
    f32x4 b0b = *(const f32x4*)(w0 + 4);
    f32x4 b1a = *(const f32x4*)w1;
    f32x4 b1b = *(const f32x4*)(w1 + 4);
    bf16x8 bf0, bf1;
#pragma unroll
    for (int j = 0; j < 4; ++j) {
      bf0[j] = (bf16_t)b0a[j]; bf0[j + 4] = (bf16_t)b0b[j];
      bf1[j] = (bf16_t)b1a[j]; bf1[j + 4] = (bf16_t)b1b[j];
    }
    acc00 = __builtin_amdgcn_mfma_f32_16x16x32_bf16(af0, bf0, acc00, 0, 0, 0);
    acc01 = __builtin_amdgcn_mfma_f32_16x16x32_bf16(af0, bf1, acc01, 0, 0, 0);
    acc10 = __builtin_amdgcn_mfma_f32_16x16x32_bf16(af1, bf0, acc10, 0, 0, 0);
    acc11 = __builtin_amdgcn_mfma_f32_16x16x32_bf16(af1, bf1, acc11, 0, 0, 0);
    a0 += 32; a1 += 32; w0 += 32; w1 += 32;
  }

  float* Cz = Cp + (size_t)z * sliceElems;
  const int rb = m0 + quad * 4;
#pragma unroll
  for (int i = 0; i < 4; ++i) {
    Cz[(size_t)(rb + i) * N + n0 + l15]           = acc00[i];
    Cz[(size_t)(rb + i) * N + n0 + 16 + l15]      = acc01[i];
    Cz[(size_t)(rb + 16 + i) * N + n0 + l15]      = acc10[i];
    Cz[(size_t)(rb + 16 + i) * N + n0 + 16 + l15] = acc11[i];
  }
}

// reduce split-K partials + bias + relu; optional fp32 and/or bf16 outputs.
__global__ void epilogue_k(const float* __restrict__ Cp, size_t sliceElems, int KS,
                           const float* __restrict__ bias, int M, int N,
                           float* __restrict__ out_f32, bf16_t* __restrict__ out_bf16,
                           int relu, int packB) {
  int idx = blockIdx.x * blockDim.x + threadIdx.x;
  if (idx >= M * N) return;
  int m = idx / N, n = idx - m * N;
  float s = 0.f;
  for (int z = 0; z < KS; ++z) s += Cp[(size_t)z * sliceElems + idx];
  s += bias[n];
  if (relu) s = fmaxf(s, 0.f);
  if (out_f32)  out_f32[idx] = s;
  if (out_bf16) {
    size_t o = packB ? packed_off(m, n, MPAD / 16) : (size_t)idx;
    out_bf16[o] = (bf16_t)s;
  }
}

// ---------------- small-N GEMM: one thread per C element ----------------
__global__ void gemv_nt(const float* __restrict__ A, const float* __restrict__ W,
                        const float* __restrict__ bias, float* __restrict__ C,
                        int M, int N, int K, int relu) {
  int gid = blockIdx.x * blockDim.x + threadIdx.x;
  if (gid >= M * N) return;
  int m = gid / N, n = gid - m * N;
  const float* a = A + (size_t)m * K;
  const float* w = W + (size_t)n * K;
  float acc = 0.f;
  for (int k = 0; k < K; k += 4) {
    float4 x = *(const float4*)(a + k);
    float4 y = *(const float4*)(w + k);
    acc += x.x * y.x + x.y * y.y + x.z * y.z + x.w * y.w;
  }
  float o = acc + bias[n];
  if (relu) o = fmaxf(o, 0.f);
  C[gid] = o;
}

// ---------------- proposal prep: scores, boxes, sort keys ----------------
__device__ inline unsigned flip_f32(float f) {
  unsigned u = __float_as_uint(f);
  return (u & 0x80000000u) ? ~u : (u | 0x80000000u);
}

__global__ void proposal_prep(const float* __restrict__ cls,
                              const float* __restrict__ bbox,
                              const float* __restrict__ info,
                              float* __restrict__ props,
                              float* __restrict__ scores,
                              unsigned long long* __restrict__ keys) {
  int idx = blockIdx.x * blockDim.x + threadIdx.x;
  if (idx >= NSORT) return;
  unsigned long long key = 0ull;
  if (idx < NANCH) {
    int a = idx % 9, m = idx / 9;
    int h = m / W_FEAT, w = m - (m / W_FEAT) * W_FEAT;
    float s0 = cls[m * 18 + a], s1 = cls[m * 18 + 9 + a];
    float mx = fmaxf(s0, s1);
    float e0 = expf(s0 - mx), e1 = expf(s1 - mx);
    float sc = e1 / (e0 + e1);
    const float* d = bbox + m * 36 + a * 4;
    float dx = d[0], dy = d[1], dw = d[2], dh = d[3];
    float ax1 = ANCHORS[a][0] + w * 16.f, ay1 = ANCHORS[a][1] + h * 16.f;
    float ax2 = ANCHORS[a][2] + w * 16.f, ay2 = ANCHORS[a][3] + h * 16.f;
    float aw = ax2 - ax1 + 1.f, ah = ay2 - ay1 + 1.f;
    float cx = ax1 + 0.5f * aw, cy = ay1 + 0.5f * ah;
    float pcx = dx * aw + cx, pcy = dy * ah + cy;
    float pww = expf(dw) * aw, phh = expf(dh) * ah;
    float x1 = pcx - 0.5f * pww, y1 = pcy - 0.5f * phh;
    float x2 = pcx + 0.5f * pww, y2 = pcy + 0.5f * phh;
    float imh = info[0], imw = info[1], iscale = info[2];
    x1 = fminf(fmaxf(x1, 0.f), imw - 1.f);
    y1 = fminf(fmaxf(y1, 0.f), imh - 1.f);
    x2 = fminf(fmaxf(x2, 0.f), imw - 1.f);
    y2 = fminf(fmaxf(y2, 0.f), imh - 1.f);
    bool ok = (x2 - x1 + 1.f >= 16.f * iscale) && (y2 - y1 + 1.f >= 16.f * iscale);
    float s = ok ? sc : -INFINITY;
    *(float4*)(props + 4 * idx) = make_float4(x1, y1, x2, y2);
    scores[idx] = s;
    key = ((unsigned long long)flip_f32(s) << 32) |
          (unsigned long long)(0xFFFFFFFFu - (unsigned)idx);
  }
  keys[idx] = key;
}

// ---------------- bitonic sort (descending), 32768 u64 keys ----------------
__global__ void bitonic_global(unsigned long long* __restrict__ keys, int j, int k) {
  int i = blockIdx.x * blockDim.x + threadIdx.x;
  int l = i ^ j;
  if (l > i) {
    unsigned long long a = keys[i], b = keys[l];
    bool up = ((i & k) == 0);
    if (up ? (a < b) : (a > b)) { keys[i] = b; keys[l] = a; }
  }
}

__launch_bounds__(1024)
__global__ void bitonic_lds(unsigned long long* __restrict__ keys, int jstart, int k) {
  __shared__ unsigned long long s[2048];
  const int tid = threadIdx.x;
  const int base = blockIdx.x * 2048;
  s[tid] = keys[base + tid];
  s[tid + 1024] = keys[base + tid + 1024];
  __syncthreads();
  for (int j = jstart; j > 0; j >>= 1) {
    int il = ((tid & ~(j - 1)) << 1) | (tid & (j - 1));
    int ig = base + il;
    bool up = ((ig & k) == 0);
    unsigned long long a = s[il], b = s[il + j];
    if (up ? (a < b) : (a > b)) { s[il] = b; s[il + j] = a; }
    __syncthreads();
  }
  keys[base + tid] = s[tid];
  keys[base + tid + 1024] = s[tid + 1024];
}

// ================= NMS: parallel IoU bitmask + single-wave greedy scan ==========
__global__ void nms_gather(const unsigned long long* __restrict__ keys,
                           const float* __restrict__ props,
                           const float* __restrict__ scores,
                           float4* __restrict__ sbox, float* __restrict__ sarea,
                           float* __restrict__ sscore,
                           unsigned long long* __restrict__ vmask) {
  int j = blockIdx.x * blockDim.x + threadIdx.x;
  bool valid = false;
  float4 b = make_float4(0.f, 0.f, 0.f, 0.f);
  float s = -INFINITY, area = 0.f;
  if (j < PRE_NMS_K) {
    unsigned long long k = keys[j];
    unsigned orig = 0xFFFFFFFFu - (unsigned)(k & 0xFFFFFFFFull);
    b = *(const float4*)(props + 4 * (size_t)orig);
    s = scores[orig];
    area = (b.z - b.x + 1.f) * (b.w - b.y + 1.f);
    valid = (s != -INFINITY);
  }
  if (j < NPAD) { sbox[j] = b; sarea[j] = area; sscore[j] = s; }
  unsigned long long ball = __ballot(valid);
  if ((threadIdx.x & 63) == 0 && j < NPAD) vmask[j >> 6] = ball;
}

__global__ void nms_mask(const float4* __restrict__ sbox, const float* __restrict__ sarea,
                         unsigned long long* __restrict__ mask) {
  int idx = blockIdx.x * blockDim.x + threadIdx.x;
  if (idx >= NPAD * NW64) return;
  int j = idx / NW64, w = idx - j * NW64;
  float4 bj = sbox[j];
  float aj = sarea[j];
  unsigned long long m = 0ull;
  int kbase = w * 64;
#pragma unroll 8
  for (int b = 0; b < 64; ++b) {
    int k = kbase + b;
    float4 bk = sbox[k];
    float xx1 = fmaxf(bj.x, bk.x), yy1 = fmaxf(bj.y, bk.y);
    float xx2 = fminf(bj.z, bk.z), yy2 = fminf(bj.w, bk.w);
    float iw = fmaxf(xx2 - xx1 + 1.f, 0.f), ih = fmaxf(yy2 - yy1 + 1.f, 0.f);
    float inter = iw * ih;
    float iou = inter / (aj + sarea[k] - inter);
    if (iou > NMS_TH) m |= (1ull << b);
  }
  mask[(size_t)j * NW64 + w] = m;
}

__launch_bounds__(64)
__global__ void nms_scan(const float4* __restrict__ sbox,
                         const unsigned long long* __restrict__ vmask,
                         const unsigned long long* __restrict__ mask,
                         float* __restrict__ rois_out) {
  const int lane = threadIdx.x;
  const int w0 = 2 * lane, w1 = 2 * lane + 1;
  unsigned long long S0 = 0ull, S1 = 0ull;
  const unsigned long long V0 = (w0 < NW64) ? vmask[w0] : 0ull;
  const unsigned long long V1 = (w1 < NW64) ? vmask[w1] : 0ull;
  __shared__ int keepIdx[POST_NMS_K];
  int keeps = 0;
  for (int w = 0; w < NW64 && keeps < POST_NMS_K; ++w) {
    const int owner = w >> 1;
    unsigned long long candsrc = (w & 1) ? ((~S1) & V1) : ((~S0) & V0);
    unsigned long long cw = __shfl(candsrc, owner);
    while (cw) {
      int b = __builtin_ctzll(cw);
      int j = w * 64 + b;
      if (lane == 0) keepIdx[keeps] = j;
      keeps++;
      if (keeps == POST_NMS_K) break;
      const unsigned long long* row = mask + (size_t)j * NW64;
      if (w0 < NW64) S0 |= row[w0];
      if (w1 < NW64) S1 |= row[w1];
      candsrc = (w & 1) ? ((~S1) & V1) : ((~S0) & V0);
      unsigned long long hi = (b == 63) ? 0ull : (~0ull << (b + 1));
      cw = __shfl(candsrc, owner) & hi;
    }
  }
  __syncthreads();
  for (int t = lane; t < POST_NMS_K; t += 64) {
    int j = (t < keeps) ? keepIdx[t] : 0;
    float4 bx = sbox[j];
    *(float4*)(rois_out + 4 * t) = bx;
  }
}

// ---------------- feature transpose: [512][NPIX] -> [NPIX][512] ----------------
__launch_bounds__(256)
__global__ void transpose_feat(const float* __restrict__ in, float* __restrict__ out) {
  __shared__ float tile[32][33];
  const int p0 = blockIdx.x * 32;
  const int c0 = blockIdx.y * 32;
  const int tx = threadIdx.x & 31, ty = threadIdx.x >> 5;   // 32x8
#pragma unroll
  for (int i = 0; i < 32; i += 8) {
    int c = c0 + ty + i, p = p0 + tx;
    tile[ty + i][tx] = (p < NPIX) ? in[(size_t)c * NPIX + p] : 0.f;
  }
  __syncthreads();
#pragma unroll
  for (int i = 0; i < 32; i += 8) {
    int p = p0 + ty + i, c = c0 + tx;
    if (p < NPIX) out[(size_t)p * 512 + c] = tile[tx][ty + i];
  }
}

// ---------------- ROI max pooling, channel-parallel (packed output) ----------------
// grid (49 bins, 300 rois), 128 threads; thread owns 4 consecutive channels.
// Window math is op-identical to legacy roi_pool; max is order-independent.
__launch_bounds__(128)
__global__ void roi_pool_p(const float* __restrict__ feat_t,
                           const float* __restrict__ rois,
                           bf16_t* __restrict__ out) {
  const int b = blockIdx.x;            // bin
  const int r = blockIdx.y;            // roi
  const int ph = b / 7, pw = b - ph * 7;
  const float4 roi = *(const float4*)(rois + 4 * r);
  float rsw = rintf(roi.x * 0.0625f);
  float rsh = rintf(roi.y * 0.0625f);
  float rew = rintf(roi.z * 0.0625f);
  float reh = rintf(roi.w * 0.0625f);
  float bw = fmaxf(rew - rsw + 1.f, 1.f) / 7.f;
  float bh = fmaxf(reh - rsh + 1.f, 1.f) / 7.f;
  float hs = fminf(fmaxf(floorf(ph * bh) + rsh, 0.f), (float)H_FEAT);
  float he = fminf(fmaxf(ceilf((ph + 1) * bh) + rsh, 0.f), (float)H_FEAT);
  float wS = fminf(fmaxf(floorf(pw * bw) + rsw, 0.f), (float)W_FEAT);
  float wE = fminf(fmaxf(ceilf((pw + 1) * bw) + rsw, 0.f), (float)W_FEAT);
  const int h0 = (int)hs, h1 = (int)he, w0 = (int)wS, w1 = (int)wE;
  const int c = threadIdx.x * 4;
  f32x4 m = {-1e30f, -1e30f, -1e30f, -1e30f};
  for (int h = h0; h < h1; ++h) {
    const float* rowp = feat_t + ((size_t)(h * W_FEAT) + w0) * 512 + c;
    for (int w = w0; w < w1; ++w) {
      f32x4 v = *(const f32x4*)rowp;
#pragma unroll
      for (int j = 0; j < 4; ++j) m[j] = fmaxf(m[j], v[j]);
      rowp += 512;
    }
  }
  const int RT = MPAD / 16;
#pragma unroll
  for (int j = 0; j < 4; ++j) {
    float v = (m[j] < -1e29f) ? 0.f : m[j];
    out[packed_off(r, (c + j) * 49 + b, RT)] = (bf16_t)v;
  }
}

// ---------------- legacy ROI max pooling (fallback, row-major output) ----------------
__global__ void roi_pool(const float* __restrict__ feat,
                         const float* __restrict__ rois,
                         bf16_t* __restrict__ out) {
  const int r = blockIdx.x;
  const float4 roi = *(const float4*)(rois + 4 * r);
  float rsw = rintf(roi.x * 0.0625f);
  float rsh = rintf(roi.y * 0.0625f);
  float rew = rintf(roi.z * 0.0625f);
  float reh = rintf(roi.w * 0.0625f);
  float bw = fmaxf(rew - rsw + 1.f, 1.f) / 7.f;
  float bh = fmaxf(reh - rsh + 1.f, 1.f) / 7.f;
  for (int idx = threadIdx.x; idx < 512 * 49; idx += blockDim.x) {
    int c = idx / 49, b = idx - c * 49;
    int ph = b / 7, pw = b - ph * 7;
    float hs = fminf(fmaxf(floorf(ph * bh) + rsh, 0.f), (float)H_FEAT);
    float he = fminf(fmaxf(ceilf((ph + 1) * bh) + rsh, 0.f), (float)H_FEAT);
    float wS = fminf(fmaxf(floorf(pw * bw) + rsw, 0.f), (float)W_FEAT);
    float wE = fminf(fmaxf(ceilf((pw + 1) * bw) + rsw, 0.f), (float)W_FEAT);
    int h0 = (int)hs, h1 = (int)he, w0 = (int)wS, w1 = (int)wE;
    float m = -1e30f;
    const float* fc = feat + (size_t)c * (H_FEAT * W_FEAT);
    for (int h = h0; h < h1; ++h)
      for (int w = w0; w < w1; ++w)
        m = fmaxf(m, fc[h * W_FEAT + w]);
    out[(size_t)r * 25088 + idx] = (bf16_t)((m < -1e29f) ? 0.f : m);
  }
}

// ---------------- row softmax (300 x 32) ----------------
__global__ void softmax32(const float* __restrict__ in, float* __restrict__ out) {
  int r = blockIdx.x * blockDim.x + threadIdx.x;
  if (r >= POST_NMS_K) return;
  const float* x = in + r * 32;
  float m = x[0];
#pragma unroll
  for (int k = 1; k < 32; ++k) m = fmaxf(m, x[k]);
  float e[32]; float s = 0.f;
#pragma unroll
  for (int k = 0; k < 32; ++k) { e[k] = expf(x[k] - m); s += e[k]; }
  float inv = 1.f / s;
#pragma unroll
  for (int k = 0; k < 32; ++k) out[r * 32 + k] = e[k] * inv;
}

// ---------------- launch ----------------
extern "C" void kernel_launch(void* const* d_in, const int* in_sizes, int n_in,
                              void* d_out, int out_size, void* d_ws, size_t ws_size,
                              hipStream_t stream) {
  const float* feat    = (const float*)d_in[0];
  const float* info    = (const float*)d_in[1];
  const float* conv1_w = (const float*)d_in[2];
  const float* conv1_b = (const float*)d_in[3];
  const float* score_w = (const float*)d_in[4];
  const float* score_b = (const float*)d_in[5];
  const float* bbox_w  = (const float*)d_in[6];
  const float* bbox_b  = (const float*)d_in[7];
  const float* fc6_w   = (const float*)d_in[8];
  const float* fc6_b   = (const float*)d_in[9];
  const float* fc7_w   = (const float*)d_in[10];
  const float* fc7_b   = (const float*)d_in[11];
  const float* sfc_w   = (const float*)d_in[12];
  const float* sfc_b   = (const float*)d_in[13];
  const float* bfc_w   = (const float*)d_in[14];
  const float* bfc_b   = (const float*)d_in[15];
  float* out = (float*)d_out;
  char*  ws  = (char*)d_ws;

  size_t off = 0;
  auto alloc = [&](size_t bytes) { size_t o = off; off += (bytes + 255) & ~(size_t)255; return o; };
  float* cls    = (float*)(ws + alloc((size_t)NPIX * 18 * 4));
  float* bbx    = (float*)(ws + alloc((size_t)NPIX * 36 * 4));
  float* props  = (float*)(ws + alloc((size_t)NANCH * 4 * 4));
  float* scores = (float*)(ws + alloc((size_t)NANCH * 4));
  unsigned long long* keys = (unsigned long long*)(ws + alloc((size_t)NSORT * 8));
  float* rpn    = (float*)(ws + alloc((size_t)NPIX * 512 * 4));
  // pooled region (bf16, 320x25088 = 16.06MB) is dead after fc6 GEMM; fc7 partials overlay it.
  char*  pooled_raw = ws + alloc((size_t)MPAD * 25088 * 2);
  bf16_t* pooled = (bf16_t*)pooled_raw;
  float*  fc7P   = (float*)pooled_raw;                 // 2 x 320*4096*4 = 10.49MB  (overlay)
  float*  fc7o   = fc7P;                               // epilogue in-place on slice 0
  float* fc6P    = (float*)(ws + alloc((size_t)4 * MPAD * 4096 * 4));
  bf16_t* fc6bf  = (bf16_t*)(ws + alloc((size_t)MPAD * 4096 * 2));
  float* clsfc   = (float*)(ws + alloc((size_t)POST_NMS_K * 32 * 4));
  float* feat_t  = (float*)(ws + alloc((size_t)NPIX * 512 * 4));   // 4.9MB transposed features

  // NMS scratch overlays fc6P (21.5MB; dead until fc6 GEMM which launches after nms_scan)
  char* nmsbase = (char*)fc6P;
  float4* sbox  = (float4*)nmsbase;
  float*  sarea = (float*)(nmsbase + 96256);
  float*  sscore= (float*)(nmsbase + 120320);
  unsigned long long* vmask = (unsigned long long*)(nmsbase + 144384);
  unsigned long long* maskb = (unsigned long long*)(nmsbase + 145408);

  // packed bf16 weights (allocated LAST so fallback layout matches legacy exactly)
  bf16_t* fc6wp = (bf16_t*)(ws + alloc((size_t)4096 * 25088 * 2));  // 205.5MB
  bf16_t* fc7wp = (bf16_t*)(ws + alloc((size_t)4096 * 4096 * 2));   //  33.6MB
  const bool packed = (off <= ws_size);

  float* rois_out = out + 9600 + 38400;   // cls_prob(300x32) | box(300x128) | rois(300x4)

  // 1. RPN conv 3x3 + relu (fp32 — selection path must stay bit-stable)
  gemm_nt<1><<<dim3(512 / BN, (NPIX + BM - 1) / BM), 256, 0, stream>>>(
      feat, conv1_w, conv1_b, rpn, NPIX, 512, KCONV, 1);
  // 2. 1x1 convs (fp32)
  gemv_nt<<<(NPIX * 18 + 255) / 256, 256, 0, stream>>>(rpn, score_w, score_b, cls, NPIX, 18, 512, 0);
  gemv_nt<<<(NPIX * 36 + 255) / 256, 256, 0, stream>>>(rpn, bbox_w, bbox_b, bbx, NPIX, 36, 512, 0);
  // 3. proposals + sort keys
  proposal_prep<<<NSORT / 256, 256, 0, stream>>>(cls, bbx, info, props, scores, keys);
  // 4. bitonic sort, descending
  for (int k = 2; k <= 2048; k <<= 1)
    bitonic_lds<<<NSORT / 2048, 1024, 0, stream>>>(keys, k >> 1, k);
  for (int k = 4096; k <= NSORT; k <<= 1) {
    for (int j = k >> 1; j >= 2048; j >>= 1)
      bitonic_global<<<NSORT / 256, 256, 0, stream>>>(keys, j, k);
    bitonic_lds<<<NSORT / 2048, 1024, 0, stream>>>(keys, 1024, k);
  }
  // 5. NMS: gather -> parallel IoU bitmask -> single-wave greedy scan
  nms_gather<<<(NPAD + 255) / 256, 256, 0, stream>>>(keys, props, scores, sbox, sarea, sscore, vmask);
  nms_mask<<<(NPAD * NW64 + 255) / 256, 256, 0, stream>>>(sbox, sarea, maskb);
  nms_scan<<<1, 64, 0, stream>>>(sbox, vmask, maskb, rois_out);

  if (packed) {
    // 6. weight repack + feature transpose + channel-parallel ROI pool (packed output)
    pack_w_bf16<<<(4096 * 25088 / 8) / 256, 256, 0, stream>>>(fc6_w, fc6wp, 25088, 4096 * 25088 / 8);
    pack_w_bf16<<<(4096 * 4096 / 8) / 256, 256, 0, stream>>>(fc7_w, fc7wp, 4096, 4096 * 4096 / 8);
    transpose_feat<<<dim3((NPIX + 31) / 32, 16), 256, 0, stream>>>(feat, feat_t);
    roi_pool_p<<<dim3(49, POST_NMS_K), 128, 0, stream>>>(feat_t, rois_out, pooled);
    // 7. fc6: packed bf16 MFMA, split-K=4, then reduce+bias+relu -> packed bf16
    gemm_mfma_p<<<dim3(64, MPAD / 64, 4), 256, 0, stream>>>(
        pooled, fc6wp, fc6P, MPAD / 16, 256, 4096, 25088 / 32 / 4, (size_t)MPAD * 4096);
    epilogue_k<<<(POST_NMS_K * 4096 + 255) / 256, 256, 0, stream>>>(
        fc6P, (size_t)MPAD * 4096, 4, fc6_b, POST_NMS_K, 4096, nullptr, fc6bf, 1, 1);
    // 8. fc7: packed bf16 MFMA, split-K=2, epilogue in-place -> fp32
    gemm_mfma_p<<<dim3(64, MPAD / 64, 2), 256, 0, stream>>>(
        fc6bf, fc7wp, fc7P, MPAD / 16, 256, 4096, 4096 / 32 / 2, (size_t)MPAD * 4096);
    epilogue_k<<<(POST_NMS_K * 4096 + 255) / 256, 256, 0, stream>>>(
        fc7P, (size_t)MPAD * 4096, 2, fc7_b, POST_NMS_K, 4096, fc7o, nullptr, 1, 0);
  } else {
    // fallback: legacy path (fp32 W converted in-reg, row-major pooled)
    roi_pool<<<POST_NMS_K, 256, 0, stream>>>(feat, rois_out, pooled);
    gemm_mfma<<<dim3(64, MPAD / 64, 4), 256, 0, stream>>>(
        pooled, fc6_w, fc6P, 25088, 4096, 25088 / 32 / 4, (size_t)MPAD * 4096);
    epilogue_k<<<(POST_NMS_K * 4096 + 255) / 256, 256, 0, stream>>>(
        fc6P, (size_t)MPAD * 4096, 4, fc6_b, POST_NMS_K, 4096, nullptr, fc6bf, 1, 0);
    gemm_mfma<<<dim3(64, MPAD / 64, 2), 256, 0, stream>>>(
        fc6bf, fc7_w, fc7P, 4096, 4096, 4096 / 32 / 2, (size_t)MPAD * 4096);
    epilogue_k<<<(POST_NMS_K * 4096 + 255) / 256, 256, 0, stream>>>(
        fc7P, (size_t)MPAD * 4096, 2, fc7_b, POST_NMS_K, 4096, fc7o, nullptr, 1, 0);
  }
  // 9. heads (fp32)
  gemv_nt<<<(POST_NMS_K * 32 + 255) / 256, 256, 0, stream>>>(fc7o, sfc_w, sfc_b, clsfc, POST_NMS_K, 32, 4096, 0);
  softmax32<<<(POST_NMS_K + 63) / 64, 64, 0, stream>>>(clsfc, out);
  gemv_nt<<<(POST_NMS_K * 128 + 255) / 256, 256, 0, stream>>>(fc7o, bfc_w, bfc_b, out + 9600, POST_NMS_K, 128, 4096, 0);
}